// Round 1
// baseline (470.290 us; speedup 1.0000x reference)
//
#include <hip/hip_runtime.h>
#include <cstdint>
#include <cstddef>

// ---------------------------------------------------------------------------
// GraphTransformerLayer on MI355X (gfx950)
//  - Floyd-Warshall w/ clip(10)  ==  BFS truncated at depth 9 (bitset, 1 wave/row)
//  - QKV / out-proj / FFN GEMMs: bf16 MFMA 16x16x32, 128x128x64 tile, 2-phase,
//    global_load_lds(16B) with pre-swizzled global source (linear LDS dest)
//  - Attention: flash-style, 4 waves/block, online softmax, V pre-transposed
// ---------------------------------------------------------------------------

typedef __attribute__((ext_vector_type(8))) short short8;     // 8 x bf16 (4 VGPR)
typedef __attribute__((ext_vector_type(4))) float f32x4;      // MFMA C/D frag

#define N_NODES 2048
#define DMODEL  512
#define NHEAD   8
#define DHEAD   64
#define FFDIM   2048

// ---- workspace layout (bytes) ---------------------------------------------
#define OFF_ADJB   (0)                       // u32 [2048][64]        512 KB
#define OFF_DIST   (0x80000)                 // u8  [2048][2048]      4 MB
#define OFF_XB     (0x480000)                // bf16[2048][512]       2 MB
#define OFF_WQB    (0x680000)                // bf16[512][512]        512 KB
#define OFF_WKB    (0x700000)
#define OFF_WVB    (0x780000)
#define OFF_WOB    (0x800000)
#define OFF_W1B    (0x880000)                // bf16[2048][512]       2 MB
#define OFF_W2B    (0xA80000)                // bf16[512][2048]       2 MB
#define OFF_QM     (0xC80000)                // bf16[2048][512]       2 MB
#define OFF_KM     (0xE80000)                // bf16[2048][512]       2 MB
#define OFF_VT     (0x1080000)               // bf16[512][2048]       2 MB (vT[d][n])
#define OFF_CTX    (0x1280000)               // bf16[2048][512]       2 MB
#define OFF_ATMP   (0x1480000)               // f32 [2048][512]       4 MB
#define OFF_H1     (0x1880000)               // f32 [2048][512]       4 MB
#define OFF_H1B    (0x1C80000)               // bf16[2048][512]       2 MB
#define OFF_MID    (0x1E80000)               // bf16[2048][2048]      8 MB
#define OFF_FFN2   (0x2680000)               // f32 [2048][512]       4 MB
// total 44.5 MB

__device__ __forceinline__ unsigned short f2bf(float f) {
  union { float f; unsigned u; } c; c.f = f;
  unsigned r = c.u + 0x7FFFu + ((c.u >> 16) & 1u);   // RNE
  return (unsigned short)(r >> 16);
}

// global -> LDS async, 16B per lane. HW writes LDS at wave-uniform base + lane*16.
typedef const __attribute__((address_space(1))) unsigned int* as1_u32p;
typedef __attribute__((address_space(3))) unsigned int* as3_u32p;
__device__ __forceinline__ void gload_lds16(const void* g, void* l) {
  __builtin_amdgcn_global_load_lds((as1_u32p)g, (as3_u32p)l, 16, 0, 0);
}

// ---------------------------------------------------------------------------
// f32 -> bf16 conversion (4 elems/thread)
// ---------------------------------------------------------------------------
__global__ void cvt_kernel(const float* __restrict__ in, unsigned short* __restrict__ out, int n4) {
  int i = blockIdx.x * blockDim.x + threadIdx.x;
  if (i < n4) {
    float4 v = ((const float4*)in)[i];
    unsigned short a0 = f2bf(v.x), a1 = f2bf(v.y), a2 = f2bf(v.z), a3 = f2bf(v.w);
    unsigned p0 = (unsigned)a0 | ((unsigned)a1 << 16);
    unsigned p1 = (unsigned)a2 | ((unsigned)a3 << 16);
    ((uint2*)out)[i] = make_uint2(p0, p1);
  }
}

// ---------------------------------------------------------------------------
// adj (f32 0/1) -> row bitsets, u32 [2048][64]
// ---------------------------------------------------------------------------
__global__ void pack_adj_kernel(const float* __restrict__ adj, uint32_t* __restrict__ adjb) {
  int i = blockIdx.x;
  int tid = threadIdx.x, wid = tid >> 6, lane = tid & 63;
  for (int it = 0; it < 8; ++it) {
    int jbase = it * 256 + wid * 64;
    int j = jbase + lane;
    unsigned long long m = __ballot(adj[(size_t)i * 2048 + j] > 0.0f);
    int w32 = jbase >> 5;
    if (lane == 0)  adjb[i * 64 + w32]     = (uint32_t)m;
    if (lane == 32) adjb[i * 64 + w32 + 1] = (uint32_t)(m >> 32);
  }
}

// ---------------------------------------------------------------------------
// BFS truncated at depth 9 -> dist u8 in [0,10].  One wave per source row.
// Lane owns u32 word `lane` (cols [lane*32, lane*32+32)).
// dist kept as 4 bitplanes in registers.
// ---------------------------------------------------------------------------
__global__ __launch_bounds__(64) void bfs_kernel(const uint32_t* __restrict__ adjb,
                                                 uint8_t* __restrict__ dist) {
  int i = blockIdx.x;
  int lane = threadIdx.x;
  uint32_t adjrow = adjb[i * 64 + lane];
  uint32_t diagm  = (lane == (i >> 5)) ? (1u << (i & 31)) : 0u;
  uint32_t front  = adjrow & ~diagm;          // exactly distance-1 nodes
  uint32_t reach  = front | diagm;
  // default dist = 10 (0b1010); dist=1 at front; dist=0 at diag
  uint32_t dp0 = front;
  uint32_t dp1 = ~(front | diagm);
  uint32_t dp2 = 0u;
  uint32_t dp3 = ~(front | diagm);

  for (int t = 2; t <= 9; ++t) {
    if (!__any(front != 0u)) break;
    uint32_t nreach = reach;
    for (int w = 0; w < 64; ++w) {
      uint32_t fw = __shfl(front, w);
      while (fw) {
        int b = __builtin_ctz(fw);
        fw &= fw - 1u;
        nreach |= adjb[(size_t)(w * 32 + b) * 64 + lane];
      }
    }
    uint32_t nf = nreach & ~reach;
    dp0 = (dp0 & ~nf) | ((t & 1) ? nf : 0u);
    dp1 = (dp1 & ~nf) | ((t & 2) ? nf : 0u);
    dp2 = (dp2 & ~nf) | ((t & 4) ? nf : 0u);
    dp3 = (dp3 & ~nf) | ((t & 8) ? nf : 0u);
    front = nf;
    reach = nreach;
  }

  uint32_t* drow = (uint32_t*)(dist + (size_t)i * 2048) + lane * 8;
  #pragma unroll
  for (int j0 = 0; j0 < 8; ++j0) {
    uint32_t outw = 0;
    #pragma unroll
    for (int j = 0; j < 4; ++j) {
      int bit = j0 * 4 + j;
      uint32_t d = ((dp0 >> bit) & 1u) | (((dp1 >> bit) & 1u) << 1) |
                   (((dp2 >> bit) & 1u) << 2) | (((dp3 >> bit) & 1u) << 3);
      outw |= d << (8 * j);
    }
    drow[j0] = outw;
  }
}

// ---------------------------------------------------------------------------
// GEMM core: C[128,128] += A[128,K] * W[128,K]^T   (both bf16 row-major, ld = K)
// 256 threads = 4 waves (2x2), each wave 64x64 (4x4 frags of 16x16).
// BK=64, single LDS buffer, 2 barriers/K-tile.
// LDS holds XOR-swizzled tiles via pre-swizzled GLOBAL source (linear LDS dest):
//   LDS 16B-chunk (row, kg8) holds global k-group kg8 ^ (row&7).
// ---------------------------------------------------------------------------
__device__ __forceinline__ void gemm_core(const short* __restrict__ A,
                                          const short* __restrict__ W,
                                          int K, int am0, int bn0,
                                          f32x4 acc[4][4], char* smem) {
  int tid = threadIdx.x, wid = tid >> 6, lane = tid & 63;
  int c15 = lane & 15, g = lane >> 4;
  int wm = wid >> 1, wn = wid & 1;
  char* As = smem;
  char* Bs = smem + 16384;

  for (int kt = 0; kt < K; kt += 64) {
    __syncthreads();   // previous tile's LDS reads done
    #pragma unroll
    for (int i = 0; i < 4; ++i) {
      int c   = i * 256 + tid;
      int row = c >> 3;
      int kg  = (c & 7) ^ (row & 7);
      gload_lds16(A + (size_t)(am0 + row) * K + kt + kg * 8,
                  As + i * 4096 + wid * 1024);
      gload_lds16(W + (size_t)(bn0 + row) * K + kt + kg * 8,
                  Bs + i * 4096 + wid * 1024);
    }
    __syncthreads();   // staging complete (implicit vmcnt(0))
    #pragma unroll
    for (int ks = 0; ks < 2; ++ks) {
      short8 af[4], bfr[4];
      #pragma unroll
      for (int mt = 0; mt < 4; ++mt) {
        int row   = wm * 64 + mt * 16 + c15;
        int chunk = (ks * 4 + g) ^ (row & 7);
        af[mt] = *(const short8*)(As + row * 128 + chunk * 16);
      }
      #pragma unroll
      for (int nt = 0; nt < 4; ++nt) {
        int row   = wn * 64 + nt * 16 + c15;
        int chunk = (ks * 4 + g) ^ (row & 7);
        bfr[nt] = *(const short8*)(Bs + row * 128 + chunk * 16);
      }
      #pragma unroll
      for (int mt = 0; mt < 4; ++mt)
        #pragma unroll
        for (int nt = 0; nt < 4; ++nt)
          acc[mt][nt] = __builtin_amdgcn_mfma_f32_16x16x32_bf16(af[mt], bfr[nt], acc[mt][nt], 0, 0, 0);
    }
  }
}

// MODE 0: QKV (3 weight regions; q,k -> bf16 row-major; v -> bf16 transposed vT[d][n])
// MODE 1: f32 out + bias
// MODE 2: bf16 out + bias + exact GELU
template <int MODE>
__global__ __launch_bounds__(256) void gemm_kernel(
    const short* __restrict__ A,
    const short* __restrict__ W0, const short* __restrict__ W1, const short* __restrict__ W2,
    const float* __restrict__ b0, const float* __restrict__ b1, const float* __restrict__ b2,
    unsigned short* __restrict__ outq, unsigned short* __restrict__ outk, unsigned short* __restrict__ outv,
    float* __restrict__ outf, unsigned short* __restrict__ outb,
    int K, int ldo) {
  __shared__ __align__(16) char smem[32768];
  int by = blockIdx.y;
  const short* W; const float* bias; int bn0;
  int region = 0;
  if (MODE == 0) {
    region = by >> 2;
    W    = (region == 0) ? W0 : (region == 1) ? W1 : W2;
    bias = (region == 0) ? b0 : (region == 1) ? b1 : b2;
    bn0  = (by & 3) * 128;
  } else {
    W = W0; bias = b0; bn0 = by * 128;
  }
  int am0 = blockIdx.x * 128;

  f32x4 acc[4][4] = {};
  gemm_core(A, W, K, am0, bn0, acc, smem);

  int tid = threadIdx.x, wid = tid >> 6, lane = tid & 63;
  int c15 = lane & 15, g = lane >> 4;
  int wm = wid >> 1, wn = wid & 1;

  #pragma unroll
  for (int mt = 0; mt < 4; ++mt)
    #pragma unroll
    for (int nt = 0; nt < 4; ++nt)
      #pragma unroll
      for (int r = 0; r < 4; ++r) {
        int row = am0 + wm * 64 + mt * 16 + g * 4 + r;   // D: row=(lane>>4)*4+reg
        int col = bn0 + wn * 64 + nt * 16 + c15;         // D: col=lane&15
        float v = acc[mt][nt][r] + bias[col];
        if (MODE == 0) {
          if (region == 0)      outq[(size_t)row * 512 + col] = f2bf(v);
          else if (region == 1) outk[(size_t)row * 512 + col] = f2bf(v);
          else                  outv[(size_t)col * 2048 + row] = f2bf(v);   // vT[d][n]
        } else if (MODE == 1) {
          outf[(size_t)row * ldo + col] = v;
        } else {
          float gv = 0.5f * v * (1.0f + erff(v * 0.70710678118654752f));
          outb[(size_t)row * ldo + col] = f2bf(gv);
        }
      }
}

// ---------------------------------------------------------------------------
// Flash attention. Block = 4 waves; block (br,h) does q rows [br*64, +64) of head h,
// wave w handles 16 q rows. Online softmax; P transposed via 2KB/wave LDS (swizzled).
// ---------------------------------------------------------------------------
__global__ __launch_bounds__(256) void attn_kernel(
    const short* __restrict__ qm, const short* __restrict__ km,
    const short* __restrict__ vT, const uint8_t* __restrict__ dist,
    const float* __restrict__ semb, unsigned short* __restrict__ ctx) {
  int br = blockIdx.x, h = blockIdx.y;
  int tid = threadIdx.x, wid = tid >> 6, lane = tid & 63;
  int c15 = lane & 15, g = lane >> 4;

  __shared__ float semb_s[16];
  __shared__ __align__(16) char pbuf_raw[4 * 2048];
  if (tid < 11) semb_s[tid] = semb[tid];
  __syncthreads();
  char* pbuf = pbuf_raw + wid * 2048;

  int qr0 = br * 64 + wid * 16;

  short8 aq[2];
  #pragma unroll
  for (int ks = 0; ks < 2; ++ks)
    aq[ks] = *(const short8*)(qm + (size_t)(qr0 + c15) * 512 + h * 64 + ks * 32 + g * 8);

  f32x4 o[4] = {};
  float m[4], l[4];
  #pragma unroll
  for (int r = 0; r < 4; ++r) { m[r] = -1e30f; l[r] = 0.0f; }

  for (int kv0 = 0; kv0 < 2048; kv0 += 64) {
    // --- S = Q K^T ---
    f32x4 sacc[4] = {};
    #pragma unroll
    for (int nt = 0; nt < 4; ++nt)
      #pragma unroll
      for (int ks = 0; ks < 2; ++ks) {
        short8 bk = *(const short8*)(km + (size_t)(kv0 + nt * 16 + c15) * 512 + h * 64 + ks * 32 + g * 8);
        sacc[nt] = __builtin_amdgcn_mfma_f32_16x16x32_bf16(aq[ks], bk, sacc[nt], 0, 0, 0);
      }

    // --- scale + spatial bias; row stats ---
    float sv[4][4];
    float rmax[4];
    #pragma unroll
    for (int r = 0; r < 4; ++r) rmax[r] = -1e30f;
    #pragma unroll
    for (int nt = 0; nt < 4; ++nt)
      #pragma unroll
      for (int r = 0; r < 4; ++r) {
        int q   = qr0 + g * 4 + r;
        int col = kv0 + nt * 16 + c15;
        float b = semb_s[dist[(size_t)q * 2048 + col]];
        float s = sacc[nt][r] * 0.125f + b;
        sv[nt][r] = s;
        rmax[r] = fmaxf(rmax[r], s);
      }
    #pragma unroll
    for (int r = 0; r < 4; ++r) {
      rmax[r] = fmaxf(rmax[r], __shfl_xor(rmax[r], 1));
      rmax[r] = fmaxf(rmax[r], __shfl_xor(rmax[r], 2));
      rmax[r] = fmaxf(rmax[r], __shfl_xor(rmax[r], 4));
      rmax[r] = fmaxf(rmax[r], __shfl_xor(rmax[r], 8));
    }

    // --- online softmax update ---
    float pscale[4], rsum[4];
    #pragma unroll
    for (int r = 0; r < 4; ++r) {
      float mn = fmaxf(m[r], rmax[r]);
      pscale[r] = __expf(m[r] - mn);
      m[r] = mn;
      rsum[r] = 0.0f;
    }
    #pragma unroll
    for (int nt = 0; nt < 4; ++nt)
      #pragma unroll
      for (int r = 0; r < 4; ++r) {
        float p = __expf(sv[nt][r] - m[r]);
        sv[nt][r] = p;
        rsum[r] += p;
      }
    #pragma unroll
    for (int r = 0; r < 4; ++r) {
      rsum[r] += __shfl_xor(rsum[r], 1);
      rsum[r] += __shfl_xor(rsum[r], 2);
      rsum[r] += __shfl_xor(rsum[r], 4);
      rsum[r] += __shfl_xor(rsum[r], 8);
      l[r] = l[r] * pscale[r] + rsum[r];
    }
    #pragma unroll
    for (int dt = 0; dt < 4; ++dt)
      #pragma unroll
      for (int r = 0; r < 4; ++r)
        o[dt][r] *= pscale[r];

    // --- P -> bf16, transpose via LDS (swizzle: byte ^= (q&3)<<5) ---
    #pragma unroll
    for (int nt = 0; nt < 4; ++nt)
      #pragma unroll
      for (int r = 0; r < 4; ++r) {
        int qloc = g * 4 + r;
        int colb = (nt * 16 + c15) * 2;
        int addr = qloc * 128 + (colb ^ ((qloc & 3) << 5));
        *(unsigned short*)(pbuf + addr) = f2bf(sv[nt][r]);
      }
    // same-wave RAW through LDS; compiler orders via lgkmcnt
    short8 pa[2];
    #pragma unroll
    for (int ks = 0; ks < 2; ++ks) {
      int chunk = (ks * 4 + g) ^ ((c15 & 3) << 1);
      pa[ks] = *(const short8*)(pbuf + c15 * 128 + chunk * 16);
    }

    // --- O += P V ---
    #pragma unroll
    for (int dt = 0; dt < 4; ++dt)
      #pragma unroll
      for (int ks = 0; ks < 2; ++ks) {
        short8 bv = *(const short8*)(vT + (size_t)(h * 64 + dt * 16 + c15) * 2048 + kv0 + ks * 32 + g * 8);
        o[dt] = __builtin_amdgcn_mfma_f32_16x16x32_bf16(pa[ks], bv, o[dt], 0, 0, 0);
      }
  }

  #pragma unroll
  for (int dt = 0; dt < 4; ++dt)
    #pragma unroll
    for (int r = 0; r < 4; ++r) {
      int q = qr0 + g * 4 + r;
      float ov = o[dt][r] / l[r];
      ctx[(size_t)q * 512 + h * 64 + dt * 16 + c15] = f2bf(ov);
    }
}

// ---------------------------------------------------------------------------
// LayerNorm(a + b) row-wise; optional bf16 copy of the output
// ---------------------------------------------------------------------------
template <bool WB>
__global__ __launch_bounds__(256) void ln_kernel(
    const float* __restrict__ a, const float* __restrict__ b,
    const float* __restrict__ w, const float* __restrict__ bb,
    float* __restrict__ out, unsigned short* __restrict__ outb) {
  int row = blockIdx.x, tid = threadIdx.x;
  const float* ar = a + (size_t)row * 512;
  const float* br = b + (size_t)row * 512;
  float v0 = ar[tid] + br[tid];
  float v1 = ar[tid + 256] + br[tid + 256];
  float s = v0 + v1, q = v0 * v0 + v1 * v1;
  for (int o = 32; o > 0; o >>= 1) { s += __shfl_down(s, o); q += __shfl_down(q, o); }
  __shared__ float rs[4], rq[4], bc[2];
  int wid = tid >> 6, lane = tid & 63;
  if (lane == 0) { rs[wid] = s; rq[wid] = q; }
  __syncthreads();
  if (tid == 0) {
    float S = rs[0] + rs[1] + rs[2] + rs[3];
    float Q = rq[0] + rq[1] + rq[2] + rq[3];
    float mu = S * (1.0f / 512.0f);
    bc[0] = mu;
    bc[1] = Q * (1.0f / 512.0f) - mu * mu;
  }
  __syncthreads();
  float mu = bc[0], inv = rsqrtf(bc[1] + 1e-5f);
  float o0 = (v0 - mu) * inv * w[tid] + bb[tid];
  float o1 = (v1 - mu) * inv * w[tid + 256] + bb[tid + 256];
  out[(size_t)row * 512 + tid] = o0;
  out[(size_t)row * 512 + tid + 256] = o1;
  if (WB) {
    outb[(size_t)row * 512 + tid] = f2bf(o0);
    outb[(size_t)row * 512 + tid + 256] = f2bf(o1);
  }
}

// ---------------------------------------------------------------------------
extern "C" void kernel_launch(void* const* d_in, const int* in_sizes, int n_in,
                              void* d_out, int out_size, void* d_ws, size_t ws_size,
                              hipStream_t stream) {
  (void)in_sizes; (void)n_in; (void)out_size; (void)ws_size;
  const float* x    = (const float*)d_in[0];
  const float* adj  = (const float*)d_in[1];
  const float* semb = (const float*)d_in[2];
  const float* wq   = (const float*)d_in[3];
  const float* bq   = (const float*)d_in[4];
  const float* wk   = (const float*)d_in[5];
  const float* bk   = (const float*)d_in[6];
  const float* wv   = (const float*)d_in[7];
  const float* bv   = (const float*)d_in[8];
  const float* wo   = (const float*)d_in[9];
  const float* bo   = (const float*)d_in[10];
  const float* ln1w = (const float*)d_in[11];
  const float* ln1b = (const float*)d_in[12];
  const float* w1   = (const float*)d_in[13];
  const float* b1   = (const float*)d_in[14];
  const float* w2   = (const float*)d_in[15];
  const float* b2   = (const float*)d_in[16];
  const float* ln2w = (const float*)d_in[17];
  const float* ln2b = (const float*)d_in[18];
  float* out = (float*)d_out;
  char* ws = (char*)d_ws;

  uint32_t*       adjb = (uint32_t*)(ws + OFF_ADJB);
  uint8_t*        dist = (uint8_t*)(ws + OFF_DIST);
  unsigned short* xb   = (unsigned short*)(ws + OFF_XB);
  unsigned short* wqb  = (unsigned short*)(ws + OFF_WQB);
  unsigned short* wkb  = (unsigned short*)(ws + OFF_WKB);
  unsigned short* wvb  = (unsigned short*)(ws + OFF_WVB);
  unsigned short* wob  = (unsigned short*)(ws + OFF_WOB);
  unsigned short* w1b  = (unsigned short*)(ws + OFF_W1B);
  unsigned short* w2b  = (unsigned short*)(ws + OFF_W2B);
  unsigned short* qm   = (unsigned short*)(ws + OFF_QM);
  unsigned short* km   = (unsigned short*)(ws + OFF_KM);
  unsigned short* vT   = (unsigned short*)(ws + OFF_VT);
  unsigned short* ctx  = (unsigned short*)(ws + OFF_CTX);
  float*          atmp = (float*)(ws + OFF_ATMP);
  float*          h1   = (float*)(ws + OFF_H1);
  unsigned short* h1b  = (unsigned short*)(ws + OFF_H1B);
  unsigned short* mid  = (unsigned short*)(ws + OFF_MID);
  float*          ffn2 = (float*)(ws + OFF_FFN2);

  // ---- dtype conversions ----
  cvt_kernel<<<1024, 256, 0, stream>>>(x,  xb,  262144);   // 2048*512/4
  cvt_kernel<<<256,  256, 0, stream>>>(wq, wqb, 65536);
  cvt_kernel<<<256,  256, 0, stream>>>(wk, wkb, 65536);
  cvt_kernel<<<256,  256, 0, stream>>>(wv, wvb, 65536);
  cvt_kernel<<<256,  256, 0, stream>>>(wo, wob, 65536);
  cvt_kernel<<<1024, 256, 0, stream>>>(w1, w1b, 262144);
  cvt_kernel<<<1024, 256, 0, stream>>>(w2, w2b, 262144);

  // ---- spatial distances ----
  pack_adj_kernel<<<2048, 256, 0, stream>>>(adj, adjb);
  bfs_kernel<<<2048, 64, 0, stream>>>(adjb, dist);

  // ---- QKV projection (q,k row-major; v transposed) ----
  gemm_kernel<0><<<dim3(16, 12), 256, 0, stream>>>(
      (const short*)xb, (const short*)wqb, (const short*)wkb, (const short*)wvb,
      bq, bk, bv, qm, km, vT, nullptr, nullptr, 512, 512);

  // ---- attention ----
  attn_kernel<<<dim3(32, 8), 256, 0, stream>>>(
      (const short*)qm, (const short*)km, (const short*)vT, dist, semb, ctx);

  // ---- output projection ----
  gemm_kernel<1><<<dim3(16, 4), 256, 0, stream>>>(
      (const short*)ctx, (const short*)wob, nullptr, nullptr,
      bo, nullptr, nullptr, nullptr, nullptr, nullptr, atmp, nullptr, 512, 512);

  // ---- LN1 (x + attn_out) ----
  ln_kernel<true><<<2048, 256, 0, stream>>>(x, atmp, ln1w, ln1b, h1, h1b);

  // ---- FFN ----
  gemm_kernel<2><<<dim3(16, 16), 256, 0, stream>>>(
      (const short*)h1b, (const short*)w1b, nullptr, nullptr,
      b1, nullptr, nullptr, nullptr, nullptr, nullptr, nullptr, mid, 512, 2048);
  gemm_kernel<1><<<dim3(16, 4), 256, 0, stream>>>(
      (const short*)mid, (const short*)w2b, nullptr, nullptr,
      b2, nullptr, nullptr, nullptr, nullptr, nullptr, ffn2, nullptr, 2048, 512);

  // ---- LN2 (h1 + ffn) -> output ----
  ln_kernel<false><<<2048, 256, 0, stream>>>(h1, ffn2, ln2w, ln2b, out, nullptr);
}

// Round 2
// 307.991 us; speedup vs baseline: 1.5270x; 1.5270x over previous
//
#include <hip/hip_runtime.h>
#include <cstdint>
#include <cstddef>

// ---------------------------------------------------------------------------
// GraphTransformerLayer on MI355X (gfx950)
//  - Floyd-Warshall w/ clip(10)  ==  BFS truncated at depth 9 (bitset)
//    R1: 4 waves/source, LDS frontier list, 4-wide ILP gather (was 1-wave serial)
//  - QKV / out-proj / FFN GEMMs: bf16 MFMA 16x16x32, 128x128x64 tile, 2-phase,
//    global_load_lds(16B) with pre-swizzled global source (linear LDS dest)
//  - Attention: flash-style, 4 waves/block, online softmax, V pre-transposed
// ---------------------------------------------------------------------------

typedef __attribute__((ext_vector_type(8))) short short8;     // 8 x bf16 (4 VGPR)
typedef __attribute__((ext_vector_type(4))) float f32x4;      // MFMA C/D frag

#define N_NODES 2048
#define DMODEL  512
#define NHEAD   8
#define DHEAD   64
#define FFDIM   2048

// ---- workspace layout (bytes) ---------------------------------------------
#define OFF_ADJB   (0)                       // u32 [2048][64]        512 KB
#define OFF_DIST   (0x80000)                 // u8  [2048][2048]      4 MB
#define OFF_XB     (0x480000)                // bf16[2048][512]       2 MB
#define OFF_WQB    (0x680000)                // bf16[512][512]        512 KB
#define OFF_WKB    (0x700000)
#define OFF_WVB    (0x780000)
#define OFF_WOB    (0x800000)
#define OFF_W1B    (0x880000)                // bf16[2048][512]       2 MB
#define OFF_W2B    (0xA80000)                // bf16[512][2048]       2 MB
#define OFF_QM     (0xC80000)                // bf16[2048][512]       2 MB
#define OFF_KM     (0xE80000)                // bf16[2048][512]       2 MB
#define OFF_VT     (0x1080000)               // bf16[512][2048]       2 MB (vT[d][n])
#define OFF_CTX    (0x1280000)               // bf16[2048][512]       2 MB
#define OFF_ATMP   (0x1480000)               // f32 [2048][512]       4 MB
#define OFF_H1     (0x1880000)               // f32 [2048][512]       4 MB
#define OFF_H1B    (0x1C80000)               // bf16[2048][512]       2 MB
#define OFF_MID    (0x1E80000)               // bf16[2048][2048]      8 MB
#define OFF_FFN2   (0x2680000)               // f32 [2048][512]       4 MB
// total 44.5 MB

__device__ __forceinline__ unsigned short f2bf(float f) {
  union { float f; unsigned u; } c; c.f = f;
  unsigned r = c.u + 0x7FFFu + ((c.u >> 16) & 1u);   // RNE
  return (unsigned short)(r >> 16);
}

// global -> LDS async, 16B per lane. HW writes LDS at wave-uniform base + lane*16.
typedef const __attribute__((address_space(1))) unsigned int* as1_u32p;
typedef __attribute__((address_space(3))) unsigned int* as3_u32p;
__device__ __forceinline__ void gload_lds16(const void* g, void* l) {
  __builtin_amdgcn_global_load_lds((as1_u32p)g, (as3_u32p)l, 16, 0, 0);
}

// ---------------------------------------------------------------------------
// f32 -> bf16 conversion (4 elems/thread)
// ---------------------------------------------------------------------------
__global__ void cvt_kernel(const float* __restrict__ in, unsigned short* __restrict__ out, int n4) {
  int i = blockIdx.x * blockDim.x + threadIdx.x;
  if (i < n4) {
    float4 v = ((const float4*)in)[i];
    unsigned short a0 = f2bf(v.x), a1 = f2bf(v.y), a2 = f2bf(v.z), a3 = f2bf(v.w);
    unsigned p0 = (unsigned)a0 | ((unsigned)a1 << 16);
    unsigned p1 = (unsigned)a2 | ((unsigned)a3 << 16);
    ((uint2*)out)[i] = make_uint2(p0, p1);
  }
}

// ---------------------------------------------------------------------------
// adj (f32 0/1) -> row bitsets, u32 [2048][64]
// ---------------------------------------------------------------------------
__global__ void pack_adj_kernel(const float* __restrict__ adj, uint32_t* __restrict__ adjb) {
  int i = blockIdx.x;
  int tid = threadIdx.x, wid = tid >> 6, lane = tid & 63;
  for (int it = 0; it < 8; ++it) {
    int jbase = it * 256 + wid * 64;
    int j = jbase + lane;
    unsigned long long m = __ballot(adj[(size_t)i * 2048 + j] > 0.0f);
    int w32 = jbase >> 5;
    if (lane == 0)  adjb[i * 64 + w32]     = (uint32_t)m;
    if (lane == 32) adjb[i * 64 + w32 + 1] = (uint32_t)(m >> 32);
  }
}

// ---------------------------------------------------------------------------
// BFS truncated at depth 9 -> dist u8 in [0,10].
// One block (4 waves) per source row. Lane owns u32 word `lane`.
// Per level: compact frontier into LDS list (popcount + shfl scan, no atomics),
// then 4 waves gather adj rows with 4 independent loads in flight each.
// dist kept as 4 bitplanes in registers (replicated across waves).
// ---------------------------------------------------------------------------
__global__ __launch_bounds__(256) void bfs_kernel(const uint32_t* __restrict__ adjb,
                                                  uint8_t* __restrict__ dist) {
  int i = blockIdx.x;
  int tid = threadIdx.x, wid = tid >> 6, lane = tid & 63;

  __shared__ uint16_t list_s[2048];
  __shared__ uint32_t comb[4][64];
  __shared__ uint32_t wtot[4];

  uint32_t adjrow = adjb[i * 64 + lane];
  uint32_t diagm  = (lane == (i >> 5)) ? (1u << (i & 31)) : 0u;
  uint32_t front  = adjrow & ~diagm;          // exactly distance-1 nodes
  uint32_t reach  = front | diagm;
  // default dist = 10 (0b1010); dist=1 at front; dist=0 at diag
  uint32_t dp0 = front;
  uint32_t dp1 = ~(front | diagm);
  uint32_t dp2 = 0u;
  uint32_t dp3 = dp1;

  for (int t = 2; t <= 9; ++t) {
    // --- compact frontier into list_s ---
    // thread tid handles bits [tid*8, tid*8+8) = byte (lane&3) of word (wid*16+(lane>>2))
    uint32_t fw = __shfl(front, wid * 16 + (lane >> 2));
    uint32_t fb = (fw >> ((lane & 3) * 8)) & 0xFFu;
    int cnt = __popc(fb);
    int scan = cnt;                          // wave-inclusive scan
    #pragma unroll
    for (int o = 1; o < 64; o <<= 1) {
      int u = __shfl_up(scan, o);
      if (lane >= o) scan += u;
    }
    if (lane == 63) wtot[wid] = (uint32_t)scan;
    __syncthreads();
    int w0 = (int)wtot[0], w1 = (int)wtot[1], w2 = (int)wtot[2], w3 = (int)wtot[3];
    int cnt_total = w0 + w1 + w2 + w3;
    if (cnt_total == 0) break;
    int base0 = (wid > 0 ? w0 : 0) + (wid > 1 ? w1 : 0) + (wid > 2 ? w2 : 0);
    int off = base0 + scan - cnt;            // exclusive offset for this thread
    int nodebase = tid * 8;
    while (fb) {
      int b = __builtin_ctz(fb);
      fb &= fb - 1u;
      list_s[off++] = (uint16_t)(nodebase + b);
    }
    __syncthreads();

    // --- gather: wave w takes entries [base+w*4, +4), 4 loads in flight ---
    uint32_t acc = 0;
    for (int base = wid * 4; base < cnt_total; base += 16) {
      #pragma unroll
      for (int j = 0; j < 4; ++j) {
        int k = base + j;                    // wave-uniform -> scalar branch
        if (k < cnt_total)
          acc |= adjb[(size_t)list_s[k] * 64 + lane];
      }
    }
    comb[wid][lane] = acc;
    __syncthreads();
    uint32_t nreach = reach | comb[0][lane] | comb[1][lane] | comb[2][lane] | comb[3][lane];
    uint32_t nf = nreach & ~reach;
    dp0 = (dp0 & ~nf) | ((t & 1) ? nf : 0u);
    dp1 = (dp1 & ~nf) | ((t & 2) ? nf : 0u);
    dp2 = (dp2 & ~nf) | ((t & 4) ? nf : 0u);
    dp3 = (dp3 & ~nf) | ((t & 8) ? nf : 0u);
    front = nf;
    reach = nreach;
  }

  // --- write dist row: thread tid emits bytes [tid*8, tid*8+8) as uint2 ---
  uint32_t p0 = __shfl(dp0, wid * 16 + (lane >> 2));
  uint32_t p1 = __shfl(dp1, wid * 16 + (lane >> 2));
  uint32_t p2 = __shfl(dp2, wid * 16 + (lane >> 2));
  uint32_t p3 = __shfl(dp3, wid * 16 + (lane >> 2));
  int sh = (lane & 3) * 8;
  uint32_t lo = 0, hi = 0;
  #pragma unroll
  for (int j = 0; j < 4; ++j) {
    int bit = sh + j;
    uint32_t d = ((p0 >> bit) & 1u) | (((p1 >> bit) & 1u) << 1) |
                 (((p2 >> bit) & 1u) << 2) | (((p3 >> bit) & 1u) << 3);
    lo |= d << (8 * j);
  }
  #pragma unroll
  for (int j = 0; j < 4; ++j) {
    int bit = sh + 4 + j;
    uint32_t d = ((p0 >> bit) & 1u) | (((p1 >> bit) & 1u) << 1) |
                 (((p2 >> bit) & 1u) << 2) | (((p3 >> bit) & 1u) << 3);
    hi |= d << (8 * j);
  }
  ((uint2*)(dist + (size_t)i * 2048))[tid] = make_uint2(lo, hi);
}

// ---------------------------------------------------------------------------
// GEMM core: C[128,128] += A[128,K] * W[128,K]^T   (both bf16 row-major, ld = K)
// 256 threads = 4 waves (2x2), each wave 64x64 (4x4 frags of 16x16).
// BK=64, single LDS buffer, 2 barriers/K-tile.
// LDS holds XOR-swizzled tiles via pre-swizzled GLOBAL source (linear LDS dest):
//   LDS 16B-chunk (row, kg8) holds global k-group kg8 ^ (row&7).
// ---------------------------------------------------------------------------
__device__ __forceinline__ void gemm_core(const short* __restrict__ A,
                                          const short* __restrict__ W,
                                          int K, int am0, int bn0,
                                          f32x4 acc[4][4], char* smem) {
  int tid = threadIdx.x, wid = tid >> 6, lane = tid & 63;
  int c15 = lane & 15, g = lane >> 4;
  int wm = wid >> 1, wn = wid & 1;
  char* As = smem;
  char* Bs = smem + 16384;

  for (int kt = 0; kt < K; kt += 64) {
    __syncthreads();   // previous tile's LDS reads done
    #pragma unroll
    for (int i = 0; i < 4; ++i) {
      int c   = i * 256 + tid;
      int row = c >> 3;
      int kg  = (c & 7) ^ (row & 7);
      gload_lds16(A + (size_t)(am0 + row) * K + kt + kg * 8,
                  As + i * 4096 + wid * 1024);
      gload_lds16(W + (size_t)(bn0 + row) * K + kt + kg * 8,
                  Bs + i * 4096 + wid * 1024);
    }
    __syncthreads();   // staging complete (implicit vmcnt(0))
    #pragma unroll
    for (int ks = 0; ks < 2; ++ks) {
      short8 af[4], bfr[4];
      #pragma unroll
      for (int mt = 0; mt < 4; ++mt) {
        int row   = wm * 64 + mt * 16 + c15;
        int chunk = (ks * 4 + g) ^ (row & 7);
        af[mt] = *(const short8*)(As + row * 128 + chunk * 16);
      }
      #pragma unroll
      for (int nt = 0; nt < 4; ++nt) {
        int row   = wn * 64 + nt * 16 + c15;
        int chunk = (ks * 4 + g) ^ (row & 7);
        bfr[nt] = *(const short8*)(Bs + row * 128 + chunk * 16);
      }
      #pragma unroll
      for (int mt = 0; mt < 4; ++mt)
        #pragma unroll
        for (int nt = 0; nt < 4; ++nt)
          acc[mt][nt] = __builtin_amdgcn_mfma_f32_16x16x32_bf16(af[mt], bfr[nt], acc[mt][nt], 0, 0, 0);
    }
  }
}

// MODE 0: QKV (3 weight regions; q,k -> bf16 row-major; v -> bf16 transposed vT[d][n])
// MODE 1: f32 out + bias
// MODE 2: bf16 out + bias + exact GELU
template <int MODE>
__global__ __launch_bounds__(256) void gemm_kernel(
    const short* __restrict__ A,
    const short* __restrict__ W0, const short* __restrict__ W1, const short* __restrict__ W2,
    const float* __restrict__ b0, const float* __restrict__ b1, const float* __restrict__ b2,
    unsigned short* __restrict__ outq, unsigned short* __restrict__ outk, unsigned short* __restrict__ outv,
    float* __restrict__ outf, unsigned short* __restrict__ outb,
    int K, int ldo) {
  __shared__ __align__(16) char smem[32768];
  int by = blockIdx.y;
  const short* W; const float* bias; int bn0;
  int region = 0;
  if (MODE == 0) {
    region = by >> 2;
    W    = (region == 0) ? W0 : (region == 1) ? W1 : W2;
    bias = (region == 0) ? b0 : (region == 1) ? b1 : b2;
    bn0  = (by & 3) * 128;
  } else {
    W = W0; bias = b0; bn0 = by * 128;
  }
  int am0 = blockIdx.x * 128;

  f32x4 acc[4][4] = {};
  gemm_core(A, W, K, am0, bn0, acc, smem);

  int tid = threadIdx.x, wid = tid >> 6, lane = tid & 63;
  int c15 = lane & 15, g = lane >> 4;
  int wm = wid >> 1, wn = wid & 1;

  #pragma unroll
  for (int mt = 0; mt < 4; ++mt)
    #pragma unroll
    for (int nt = 0; nt < 4; ++nt)
      #pragma unroll
      for (int r = 0; r < 4; ++r) {
        int row = am0 + wm * 64 + mt * 16 + g * 4 + r;   // D: row=(lane>>4)*4+reg
        int col = bn0 + wn * 64 + nt * 16 + c15;         // D: col=lane&15
        float v = acc[mt][nt][r] + bias[col];
        if (MODE == 0) {
          if (region == 0)      outq[(size_t)row * 512 + col] = f2bf(v);
          else if (region == 1) outk[(size_t)row * 512 + col] = f2bf(v);
          else                  outv[(size_t)col * 2048 + row] = f2bf(v);   // vT[d][n]
        } else if (MODE == 1) {
          outf[(size_t)row * ldo + col] = v;
        } else {
          float gv = 0.5f * v * (1.0f + erff(v * 0.70710678118654752f));
          outb[(size_t)row * ldo + col] = f2bf(gv);
        }
      }
}

// ---------------------------------------------------------------------------
// Flash attention. Block = 4 waves; block (br,h) does q rows [br*64, +64) of head h,
// wave w handles 16 q rows. Online softmax; P transposed via 2KB/wave LDS (swizzled).
// ---------------------------------------------------------------------------
__global__ __launch_bounds__(256) void attn_kernel(
    const short* __restrict__ qm, const short* __restrict__ km,
    const short* __restrict__ vT, const uint8_t* __restrict__ dist,
    const float* __restrict__ semb, unsigned short* __restrict__ ctx) {
  int br = blockIdx.x, h = blockIdx.y;
  int tid = threadIdx.x, wid = tid >> 6, lane = tid & 63;
  int c15 = lane & 15, g = lane >> 4;

  __shared__ float semb_s[16];
  __shared__ __align__(16) char pbuf_raw[4 * 2048];
  if (tid < 11) semb_s[tid] = semb[tid];
  __syncthreads();
  char* pbuf = pbuf_raw + wid * 2048;

  int qr0 = br * 64 + wid * 16;

  short8 aq[2];
  #pragma unroll
  for (int ks = 0; ks < 2; ++ks)
    aq[ks] = *(const short8*)(qm + (size_t)(qr0 + c15) * 512 + h * 64 + ks * 32 + g * 8);

  f32x4 o[4] = {};
  float m[4], l[4];
  #pragma unroll
  for (int r = 0; r < 4; ++r) { m[r] = -1e30f; l[r] = 0.0f; }

  for (int kv0 = 0; kv0 < 2048; kv0 += 64) {
    // --- S = Q K^T ---
    f32x4 sacc[4] = {};
    #pragma unroll
    for (int nt = 0; nt < 4; ++nt)
      #pragma unroll
      for (int ks = 0; ks < 2; ++ks) {
        short8 bk = *(const short8*)(km + (size_t)(kv0 + nt * 16 + c15) * 512 + h * 64 + ks * 32 + g * 8);
        sacc[nt] = __builtin_amdgcn_mfma_f32_16x16x32_bf16(aq[ks], bk, sacc[nt], 0, 0, 0);
      }

    // --- scale + spatial bias; row stats ---
    float sv[4][4];
    float rmax[4];
    #pragma unroll
    for (int r = 0; r < 4; ++r) rmax[r] = -1e30f;
    #pragma unroll
    for (int nt = 0; nt < 4; ++nt)
      #pragma unroll
      for (int r = 0; r < 4; ++r) {
        int q   = qr0 + g * 4 + r;
        int col = kv0 + nt * 16 + c15;
        float b = semb_s[dist[(size_t)q * 2048 + col]];
        float s = sacc[nt][r] * 0.125f + b;
        sv[nt][r] = s;
        rmax[r] = fmaxf(rmax[r], s);
      }
    #pragma unroll
    for (int r = 0; r < 4; ++r) {
      rmax[r] = fmaxf(rmax[r], __shfl_xor(rmax[r], 1));
      rmax[r] = fmaxf(rmax[r], __shfl_xor(rmax[r], 2));
      rmax[r] = fmaxf(rmax[r], __shfl_xor(rmax[r], 4));
      rmax[r] = fmaxf(rmax[r], __shfl_xor(rmax[r], 8));
    }

    // --- online softmax update ---
    float pscale[4], rsum[4];
    #pragma unroll
    for (int r = 0; r < 4; ++r) {
      float mn = fmaxf(m[r], rmax[r]);
      pscale[r] = __expf(m[r] - mn);
      m[r] = mn;
      rsum[r] = 0.0f;
    }
    #pragma unroll
    for (int nt = 0; nt < 4; ++nt)
      #pragma unroll
      for (int r = 0; r < 4; ++r) {
        float p = __expf(sv[nt][r] - m[r]);
        sv[nt][r] = p;
        rsum[r] += p;
      }
    #pragma unroll
    for (int r = 0; r < 4; ++r) {
      rsum[r] += __shfl_xor(rsum[r], 1);
      rsum[r] += __shfl_xor(rsum[r], 2);
      rsum[r] += __shfl_xor(rsum[r], 4);
      rsum[r] += __shfl_xor(rsum[r], 8);
      l[r] = l[r] * pscale[r] + rsum[r];
    }
    #pragma unroll
    for (int dt = 0; dt < 4; ++dt)
      #pragma unroll
      for (int r = 0; r < 4; ++r)
        o[dt][r] *= pscale[r];

    // --- P -> bf16, transpose via LDS (swizzle: byte ^= (q&3)<<5) ---
    #pragma unroll
    for (int nt = 0; nt < 4; ++nt)
      #pragma unroll
      for (int r = 0; r < 4; ++r) {
        int qloc = g * 4 + r;
        int colb = (nt * 16 + c15) * 2;
        int addr = qloc * 128 + (colb ^ ((qloc & 3) << 5));
        *(unsigned short*)(pbuf + addr) = f2bf(sv[nt][r]);
      }
    // same-wave RAW through LDS; compiler orders via lgkmcnt
    short8 pa[2];
    #pragma unroll
    for (int ks = 0; ks < 2; ++ks) {
      int chunk = (ks * 4 + g) ^ ((c15 & 3) << 1);
      pa[ks] = *(const short8*)(pbuf + c15 * 128 + chunk * 16);
    }

    // --- O += P V ---
    #pragma unroll
    for (int dt = 0; dt < 4; ++dt)
      #pragma unroll
      for (int ks = 0; ks < 2; ++ks) {
        short8 bv = *(const short8*)(vT + (size_t)(h * 64 + dt * 16 + c15) * 2048 + kv0 + ks * 32 + g * 8);
        o[dt] = __builtin_amdgcn_mfma_f32_16x16x32_bf16(pa[ks], bv, o[dt], 0, 0, 0);
      }
  }

  #pragma unroll
  for (int dt = 0; dt < 4; ++dt)
    #pragma unroll
    for (int r = 0; r < 4; ++r) {
      int q = qr0 + g * 4 + r;
      float ov = o[dt][r] / l[r];
      ctx[(size_t)q * 512 + h * 64 + dt * 16 + c15] = f2bf(ov);
    }
}

// ---------------------------------------------------------------------------
// LayerNorm(a + b) row-wise; optional bf16 copy of the output
// ---------------------------------------------------------------------------
template <bool WB>
__global__ __launch_bounds__(256) void ln_kernel(
    const float* __restrict__ a, const float* __restrict__ b,
    const float* __restrict__ w, const float* __restrict__ bb,
    float* __restrict__ out, unsigned short* __restrict__ outb) {
  int row = blockIdx.x, tid = threadIdx.x;
  const float* ar = a + (size_t)row * 512;
  const float* br = b + (size_t)row * 512;
  float v0 = ar[tid] + br[tid];
  float v1 = ar[tid + 256] + br[tid + 256];
  float s = v0 + v1, q = v0 * v0 + v1 * v1;
  for (int o = 32; o > 0; o >>= 1) { s += __shfl_down(s, o); q += __shfl_down(q, o); }
  __shared__ float rs[4], rq[4], bc[2];
  int wid = tid >> 6, lane = tid & 63;
  if (lane == 0) { rs[wid] = s; rq[wid] = q; }
  __syncthreads();
  if (tid == 0) {
    float S = rs[0] + rs[1] + rs[2] + rs[3];
    float Q = rq[0] + rq[1] + rq[2] + rq[3];
    float mu = S * (1.0f / 512.0f);
    bc[0] = mu;
    bc[1] = Q * (1.0f / 512.0f) - mu * mu;
  }
  __syncthreads();
  float mu = bc[0], inv = rsqrtf(bc[1] + 1e-5f);
  float o0 = (v0 - mu) * inv * w[tid] + bb[tid];
  float o1 = (v1 - mu) * inv * w[tid + 256] + bb[tid + 256];
  out[(size_t)row * 512 + tid] = o0;
  out[(size_t)row * 512 + tid + 256] = o1;
  if (WB) {
    outb[(size_t)row * 512 + tid] = f2bf(o0);
    outb[(size_t)row * 512 + tid + 256] = f2bf(o1);
  }
}

// ---------------------------------------------------------------------------
extern "C" void kernel_launch(void* const* d_in, const int* in_sizes, int n_in,
                              void* d_out, int out_size, void* d_ws, size_t ws_size,
                              hipStream_t stream) {
  (void)in_sizes; (void)n_in; (void)out_size; (void)ws_size;
  const float* x    = (const float*)d_in[0];
  const float* adj  = (const float*)d_in[1];
  const float* semb = (const float*)d_in[2];
  const float* wq   = (const float*)d_in[3];
  const float* bq   = (const float*)d_in[4];
  const float* wk   = (const float*)d_in[5];
  const float* bk   = (const float*)d_in[6];
  const float* wv   = (const float*)d_in[7];
  const float* bv   = (const float*)d_in[8];
  const float* wo   = (const float*)d_in[9];
  const float* bo   = (const float*)d_in[10];
  const float* ln1w = (const float*)d_in[11];
  const float* ln1b = (const float*)d_in[12];
  const float* w1   = (const float*)d_in[13];
  const float* b1   = (const float*)d_in[14];
  const float* w2   = (const float*)d_in[15];
  const float* b2   = (const float*)d_in[16];
  const float* ln2w = (const float*)d_in[17];
  const float* ln2b = (const float*)d_in[18];
  float* out = (float*)d_out;
  char* ws = (char*)d_ws;

  uint32_t*       adjb = (uint32_t*)(ws + OFF_ADJB);
  uint8_t*        dist = (uint8_t*)(ws + OFF_DIST);
  unsigned short* xb   = (unsigned short*)(ws + OFF_XB);
  unsigned short* wqb  = (unsigned short*)(ws + OFF_WQB);
  unsigned short* wkb  = (unsigned short*)(ws + OFF_WKB);
  unsigned short* wvb  = (unsigned short*)(ws + OFF_WVB);
  unsigned short* wob  = (unsigned short*)(ws + OFF_WOB);
  unsigned short* w1b  = (unsigned short*)(ws + OFF_W1B);
  unsigned short* w2b  = (unsigned short*)(ws + OFF_W2B);
  unsigned short* qm   = (unsigned short*)(ws + OFF_QM);
  unsigned short* km   = (unsigned short*)(ws + OFF_KM);
  unsigned short* vT   = (unsigned short*)(ws + OFF_VT);
  unsigned short* ctx  = (unsigned short*)(ws + OFF_CTX);
  float*          atmp = (float*)(ws + OFF_ATMP);
  float*          h1   = (float*)(ws + OFF_H1);
  unsigned short* h1b  = (unsigned short*)(ws + OFF_H1B);
  unsigned short* mid  = (unsigned short*)(ws + OFF_MID);
  float*          ffn2 = (float*)(ws + OFF_FFN2);

  // ---- dtype conversions ----
  cvt_kernel<<<1024, 256, 0, stream>>>(x,  xb,  262144);   // 2048*512/4
  cvt_kernel<<<256,  256, 0, stream>>>(wq, wqb, 65536);
  cvt_kernel<<<256,  256, 0, stream>>>(wk, wkb, 65536);
  cvt_kernel<<<256,  256, 0, stream>>>(wv, wvb, 65536);
  cvt_kernel<<<256,  256, 0, stream>>>(wo, wob, 65536);
  cvt_kernel<<<1024, 256, 0, stream>>>(w1, w1b, 262144);
  cvt_kernel<<<1024, 256, 0, stream>>>(w2, w2b, 262144);

  // ---- spatial distances ----
  pack_adj_kernel<<<2048, 256, 0, stream>>>(adj, adjb);
  bfs_kernel<<<2048, 256, 0, stream>>>(adjb, dist);

  // ---- QKV projection (q,k row-major; v transposed) ----
  gemm_kernel<0><<<dim3(16, 12), 256, 0, stream>>>(
      (const short*)xb, (const short*)wqb, (const short*)wkb, (const short*)wvb,
      bq, bk, bv, qm, km, vT, nullptr, nullptr, 512, 512);

  // ---- attention ----
  attn_kernel<<<dim3(32, 8), 256, 0, stream>>>(
      (const short*)qm, (const short*)km, (const short*)vT, dist, semb, ctx);

  // ---- output projection ----
  gemm_kernel<1><<<dim3(16, 4), 256, 0, stream>>>(
      (const short*)ctx, (const short*)wob, nullptr, nullptr,
      bo, nullptr, nullptr, nullptr, nullptr, nullptr, atmp, nullptr, 512, 512);

  // ---- LN1 (x + attn_out) ----
  ln_kernel<true><<<2048, 256, 0, stream>>>(x, atmp, ln1w, ln1b, h1, h1b);

  // ---- FFN ----
  gemm_kernel<2><<<dim3(16, 16), 256, 0, stream>>>(
      (const short*)h1b, (const short*)w1b, nullptr, nullptr,
      b1, nullptr, nullptr, nullptr, nullptr, nullptr, nullptr, mid, 512, 2048);
  gemm_kernel<1><<<dim3(16, 4), 256, 0, stream>>>(
      (const short*)mid, (const short*)w2b, nullptr, nullptr,
      b2, nullptr, nullptr, nullptr, nullptr, nullptr, ffn2, nullptr, 2048, 512);

  // ---- LN2 (h1 + ffn) -> output ----
  ln_kernel<false><<<2048, 256, 0, stream>>>(h1, ffn2, ln2w, ln2b, out, nullptr);
}

// Round 3
// 260.278 us; speedup vs baseline: 1.8069x; 1.1833x over previous
//
#include <hip/hip_runtime.h>
#include <cstdint>
#include <cstddef>

// ---------------------------------------------------------------------------
// GraphTransformerLayer on MI355X (gfx950)
//  - Floyd-Warshall w/ clip(10)  ==  BFS truncated at depth 9 (bitset)
//  - QKV / out-proj / FFN GEMMs: bf16 MFMA 16x16x32, 128x128x64 tile, 2-phase,
//    global_load_lds(16B) with pre-swizzled global source (linear LDS dest)
//  - Attention R3: block = 16 q-rows x 1 head, 4 waves each own a 512-col KV
//    range (independent online softmax), LDS combine at end. 1024 blocks ->
//    50% occupancy (was 1 block/CU). dist tiles staged via global_load_lds.
// ---------------------------------------------------------------------------

typedef __attribute__((ext_vector_type(8))) short short8;     // 8 x bf16 (4 VGPR)
typedef __attribute__((ext_vector_type(4))) float f32x4;      // MFMA C/D frag

#define N_NODES 2048
#define DMODEL  512
#define NHEAD   8
#define DHEAD   64
#define FFDIM   2048

// ---- workspace layout (bytes) ---------------------------------------------
#define OFF_ADJB   (0)                       // u32 [2048][64]        512 KB
#define OFF_DIST   (0x80000)                 // u8  [2048][2048]      4 MB
#define OFF_XB     (0x480000)                // bf16[2048][512]       2 MB
#define OFF_WQB    (0x680000)                // bf16[512][512]        512 KB
#define OFF_WKB    (0x700000)
#define OFF_WVB    (0x780000)
#define OFF_WOB    (0x800000)
#define OFF_W1B    (0x880000)                // bf16[2048][512]       2 MB
#define OFF_W2B    (0xA80000)                // bf16[512][2048]       2 MB
#define OFF_QM     (0xC80000)                // bf16[2048][512]       2 MB
#define OFF_KM     (0xE80000)                // bf16[2048][512]       2 MB
#define OFF_VT     (0x1080000)               // bf16[512][2048]       2 MB (vT[d][n])
#define OFF_CTX    (0x1280000)               // bf16[2048][512]       2 MB
#define OFF_ATMP   (0x1480000)               // f32 [2048][512]       4 MB
#define OFF_H1     (0x1880000)               // f32 [2048][512]       4 MB
#define OFF_H1B    (0x1C80000)               // bf16[2048][512]       2 MB
#define OFF_MID    (0x1E80000)               // bf16[2048][2048]      8 MB
#define OFF_FFN2   (0x2680000)               // f32 [2048][512]       4 MB
// total 44.5 MB

__device__ __forceinline__ unsigned short f2bf(float f) {
  union { float f; unsigned u; } c; c.f = f;
  unsigned r = c.u + 0x7FFFu + ((c.u >> 16) & 1u);   // RNE
  return (unsigned short)(r >> 16);
}

// global -> LDS async, 16B per lane. HW writes LDS at wave-uniform base + lane*16.
typedef const __attribute__((address_space(1))) unsigned int* as1_u32p;
typedef __attribute__((address_space(3))) unsigned int* as3_u32p;
__device__ __forceinline__ void gload_lds16(const void* g, void* l) {
  __builtin_amdgcn_global_load_lds((as1_u32p)g, (as3_u32p)l, 16, 0, 0);
}

// ---------------------------------------------------------------------------
// fused f32 -> bf16 conversion for all 7 arrays (4 elems/thread)
// segment boundaries in uint4-groups: x 262144 | wq/wk/wv/wo 65536 ea | w1 262144 | w2 262144
// ---------------------------------------------------------------------------
__global__ void cvt_all_kernel(const float* __restrict__ x,
                               const float* __restrict__ wq, const float* __restrict__ wk,
                               const float* __restrict__ wv, const float* __restrict__ wo,
                               const float* __restrict__ w1, const float* __restrict__ w2,
                               unsigned short* __restrict__ xb,
                               unsigned short* __restrict__ wqb, unsigned short* __restrict__ wkb,
                               unsigned short* __restrict__ wvb, unsigned short* __restrict__ wob,
                               unsigned short* __restrict__ w1b, unsigned short* __restrict__ w2b) {
  int i = blockIdx.x * 256 + threadIdx.x;       // 0 .. 1048575
  const float* src; unsigned short* dst; int off;
  if (i < 262144)      { src = x;  dst = xb;  off = i; }
  else if (i < 327680) { src = wq; dst = wqb; off = i - 262144; }
  else if (i < 393216) { src = wk; dst = wkb; off = i - 327680; }
  else if (i < 458752) { src = wv; dst = wvb; off = i - 393216; }
  else if (i < 524288) { src = wo; dst = wob; off = i - 458752; }
  else if (i < 786432) { src = w1; dst = w1b; off = i - 524288; }
  else                 { src = w2; dst = w2b; off = i - 786432; }
  float4 v = ((const float4*)src)[off];
  unsigned p0 = (unsigned)f2bf(v.x) | ((unsigned)f2bf(v.y) << 16);
  unsigned p1 = (unsigned)f2bf(v.z) | ((unsigned)f2bf(v.w) << 16);
  ((uint2*)dst)[off] = make_uint2(p0, p1);
}

// ---------------------------------------------------------------------------
// adj (f32 0/1) -> row bitsets, u32 [2048][64]
// ---------------------------------------------------------------------------
__global__ void pack_adj_kernel(const float* __restrict__ adj, uint32_t* __restrict__ adjb) {
  int i = blockIdx.x;
  int tid = threadIdx.x, wid = tid >> 6, lane = tid & 63;
  for (int it = 0; it < 8; ++it) {
    int jbase = it * 256 + wid * 64;
    int j = jbase + lane;
    unsigned long long m = __ballot(adj[(size_t)i * 2048 + j] > 0.0f);
    int w32 = jbase >> 5;
    if (lane == 0)  adjb[i * 64 + w32]     = (uint32_t)m;
    if (lane == 32) adjb[i * 64 + w32 + 1] = (uint32_t)(m >> 32);
  }
}

// ---------------------------------------------------------------------------
// BFS truncated at depth 9 -> dist u8 in [0,10].
// One block (4 waves) per source row. Lane owns u32 word `lane`.
// Per level: compact frontier into LDS list (popcount + shfl scan, no atomics),
// then 4 waves gather adj rows with 4 independent loads in flight each.
// ---------------------------------------------------------------------------
__global__ __launch_bounds__(256) void bfs_kernel(const uint32_t* __restrict__ adjb,
                                                  uint8_t* __restrict__ dist) {
  int i = blockIdx.x;
  int tid = threadIdx.x, wid = tid >> 6, lane = tid & 63;

  __shared__ uint16_t list_s[2048];
  __shared__ uint32_t comb[4][64];
  __shared__ uint32_t wtot[4];

  uint32_t adjrow = adjb[i * 64 + lane];
  uint32_t diagm  = (lane == (i >> 5)) ? (1u << (i & 31)) : 0u;
  uint32_t front  = adjrow & ~diagm;          // exactly distance-1 nodes
  uint32_t reach  = front | diagm;
  uint32_t dp0 = front;
  uint32_t dp1 = ~(front | diagm);
  uint32_t dp2 = 0u;
  uint32_t dp3 = dp1;

  for (int t = 2; t <= 9; ++t) {
    uint32_t fw = __shfl(front, wid * 16 + (lane >> 2));
    uint32_t fb = (fw >> ((lane & 3) * 8)) & 0xFFu;
    int cnt = __popc(fb);
    int scan = cnt;                          // wave-inclusive scan
    #pragma unroll
    for (int o = 1; o < 64; o <<= 1) {
      int u = __shfl_up(scan, o);
      if (lane >= o) scan += u;
    }
    if (lane == 63) wtot[wid] = (uint32_t)scan;
    __syncthreads();
    int w0 = (int)wtot[0], w1 = (int)wtot[1], w2 = (int)wtot[2], w3 = (int)wtot[3];
    int cnt_total = w0 + w1 + w2 + w3;
    if (cnt_total == 0) break;
    int base0 = (wid > 0 ? w0 : 0) + (wid > 1 ? w1 : 0) + (wid > 2 ? w2 : 0);
    int off = base0 + scan - cnt;            // exclusive offset for this thread
    int nodebase = tid * 8;
    while (fb) {
      int b = __builtin_ctz(fb);
      fb &= fb - 1u;
      list_s[off++] = (uint16_t)(nodebase + b);
    }
    __syncthreads();

    uint32_t acc = 0;
    for (int base = wid * 4; base < cnt_total; base += 16) {
      #pragma unroll
      for (int j = 0; j < 4; ++j) {
        int k = base + j;                    // wave-uniform -> scalar branch
        if (k < cnt_total)
          acc |= adjb[(size_t)list_s[k] * 64 + lane];
      }
    }
    comb[wid][lane] = acc;
    __syncthreads();
    uint32_t nreach = reach | comb[0][lane] | comb[1][lane] | comb[2][lane] | comb[3][lane];
    uint32_t nf = nreach & ~reach;
    dp0 = (dp0 & ~nf) | ((t & 1) ? nf : 0u);
    dp1 = (dp1 & ~nf) | ((t & 2) ? nf : 0u);
    dp2 = (dp2 & ~nf) | ((t & 4) ? nf : 0u);
    dp3 = (dp3 & ~nf) | ((t & 8) ? nf : 0u);
    front = nf;
    reach = nreach;
  }

  uint32_t p0 = __shfl(dp0, wid * 16 + (lane >> 2));
  uint32_t p1 = __shfl(dp1, wid * 16 + (lane >> 2));
  uint32_t p2 = __shfl(dp2, wid * 16 + (lane >> 2));
  uint32_t p3 = __shfl(dp3, wid * 16 + (lane >> 2));
  int sh = (lane & 3) * 8;
  uint32_t lo = 0, hi = 0;
  #pragma unroll
  for (int j = 0; j < 4; ++j) {
    int bit = sh + j;
    uint32_t d = ((p0 >> bit) & 1u) | (((p1 >> bit) & 1u) << 1) |
                 (((p2 >> bit) & 1u) << 2) | (((p3 >> bit) & 1u) << 3);
    lo |= d << (8 * j);
  }
  #pragma unroll
  for (int j = 0; j < 4; ++j) {
    int bit = sh + 4 + j;
    uint32_t d = ((p0 >> bit) & 1u) | (((p1 >> bit) & 1u) << 1) |
                 (((p2 >> bit) & 1u) << 2) | (((p3 >> bit) & 1u) << 3);
    hi |= d << (8 * j);
  }
  ((uint2*)(dist + (size_t)i * 2048))[tid] = make_uint2(lo, hi);
}

// ---------------------------------------------------------------------------
// GEMM core: C[128,128] += A[128,K] * W[128,K]^T   (both bf16 row-major, ld = K)
// ---------------------------------------------------------------------------
__device__ __forceinline__ void gemm_core(const short* __restrict__ A,
                                          const short* __restrict__ W,
                                          int K, int am0, int bn0,
                                          f32x4 acc[4][4], char* smem) {
  int tid = threadIdx.x, wid = tid >> 6, lane = tid & 63;
  int c15 = lane & 15, g = lane >> 4;
  int wm = wid >> 1, wn = wid & 1;
  char* As = smem;
  char* Bs = smem + 16384;

  for (int kt = 0; kt < K; kt += 64) {
    __syncthreads();   // previous tile's LDS reads done
    #pragma unroll
    for (int i = 0; i < 4; ++i) {
      int c   = i * 256 + tid;
      int row = c >> 3;
      int kg  = (c & 7) ^ (row & 7);
      gload_lds16(A + (size_t)(am0 + row) * K + kt + kg * 8,
                  As + i * 4096 + wid * 1024);
      gload_lds16(W + (size_t)(bn0 + row) * K + kt + kg * 8,
                  Bs + i * 4096 + wid * 1024);
    }
    __syncthreads();   // staging complete (implicit vmcnt(0))
    #pragma unroll
    for (int ks = 0; ks < 2; ++ks) {
      short8 af[4], bfr[4];
      #pragma unroll
      for (int mt = 0; mt < 4; ++mt) {
        int row   = wm * 64 + mt * 16 + c15;
        int chunk = (ks * 4 + g) ^ (row & 7);
        af[mt] = *(const short8*)(As + row * 128 + chunk * 16);
      }
      #pragma unroll
      for (int nt = 0; nt < 4; ++nt) {
        int row   = wn * 64 + nt * 16 + c15;
        int chunk = (ks * 4 + g) ^ (row & 7);
        bfr[nt] = *(const short8*)(Bs + row * 128 + chunk * 16);
      }
      #pragma unroll
      for (int mt = 0; mt < 4; ++mt)
        #pragma unroll
        for (int nt = 0; nt < 4; ++nt)
          acc[mt][nt] = __builtin_amdgcn_mfma_f32_16x16x32_bf16(af[mt], bfr[nt], acc[mt][nt], 0, 0, 0);
    }
  }
}

// MODE 0: QKV (3 weight regions; q,k -> bf16 row-major; v -> bf16 transposed vT[d][n])
// MODE 1: f32 out + bias
// MODE 2: bf16 out + bias + exact GELU
template <int MODE>
__global__ __launch_bounds__(256) void gemm_kernel(
    const short* __restrict__ A,
    const short* __restrict__ W0, const short* __restrict__ W1, const short* __restrict__ W2,
    const float* __restrict__ b0, const float* __restrict__ b1, const float* __restrict__ b2,
    unsigned short* __restrict__ outq, unsigned short* __restrict__ outk, unsigned short* __restrict__ outv,
    float* __restrict__ outf, unsigned short* __restrict__ outb,
    int K, int ldo) {
  __shared__ __align__(16) char smem[32768];
  int by = blockIdx.y;
  const short* W; const float* bias; int bn0;
  int region = 0;
  if (MODE == 0) {
    region = by >> 2;
    W    = (region == 0) ? W0 : (region == 1) ? W1 : W2;
    bias = (region == 0) ? b0 : (region == 1) ? b1 : b2;
    bn0  = (by & 3) * 128;
  } else {
    W = W0; bias = b0; bn0 = by * 128;
  }
  int am0 = blockIdx.x * 128;

  f32x4 acc[4][4] = {};
  gemm_core(A, W, K, am0, bn0, acc, smem);

  int tid = threadIdx.x, wid = tid >> 6, lane = tid & 63;
  int c15 = lane & 15, g = lane >> 4;
  int wm = wid >> 1, wn = wid & 1;

  #pragma unroll
  for (int mt = 0; mt < 4; ++mt)
    #pragma unroll
    for (int nt = 0; nt < 4; ++nt)
      #pragma unroll
      for (int r = 0; r < 4; ++r) {
        int row = am0 + wm * 64 + mt * 16 + g * 4 + r;   // D: row=(lane>>4)*4+reg
        int col = bn0 + wn * 64 + nt * 16 + c15;         // D: col=lane&15
        float v = acc[mt][nt][r] + bias[col];
        if (MODE == 0) {
          if (region == 0)      outq[(size_t)row * 512 + col] = f2bf(v);
          else if (region == 1) outk[(size_t)row * 512 + col] = f2bf(v);
          else                  outv[(size_t)col * 2048 + row] = f2bf(v);   // vT[d][n]
        } else if (MODE == 1) {
          outf[(size_t)row * ldo + col] = v;
        } else {
          float gv = 0.5f * v * (1.0f + erff(v * 0.70710678118654752f));
          outb[(size_t)row * ldo + col] = f2bf(gv);
        }
      }
}

// ---------------------------------------------------------------------------
// Flash attention R3.
// Block (qt, h): q rows [qt*16, +16) of head h. 4 waves; wave w owns KV cols
// [w*512, +512) with an independent online softmax; partials (m,l,O) combined
// via LDS at the end. dist tiles (16x64 u8) staged by one global_load_lds.
// LDS union: phase1 {pbuf 4x2KB | dbuf 4x1KB} / phase2 {o_s 16KB | ml_s 512B}.
// ---------------------------------------------------------------------------
__global__ __launch_bounds__(256, 4) void attn_kernel(
    const short* __restrict__ qm, const short* __restrict__ km,
    const short* __restrict__ vT, const uint8_t* __restrict__ dist,
    const float* __restrict__ semb, unsigned short* __restrict__ ctx) {
  int qt = blockIdx.x, h = blockIdx.y;
  int tid = threadIdx.x, wid = tid >> 6, lane = tid & 63;
  int c15 = lane & 15, g = lane >> 4;

  __shared__ __align__(16) char lds[16896];
  __shared__ float semb_s[12];
  if (tid < 11) semb_s[tid] = semb[tid];
  __syncthreads();

  char* pbuf = lds + wid * 2048;
  uint8_t* dbuf = (uint8_t*)(lds + 8192 + wid * 1024);

  int qr0 = qt * 16;

  short8 aq[2];
  #pragma unroll
  for (int ks = 0; ks < 2; ++ks)
    aq[ks] = *(const short8*)(qm + (size_t)(qr0 + c15) * 512 + h * 64 + ks * 32 + g * 8);

  f32x4 o[4] = {};
  float m[4], l[4];
  #pragma unroll
  for (int r = 0; r < 4; ++r) { m[r] = -1e30f; l[r] = 0.0f; }

  for (int t = 0; t < 8; ++t) {
    int kv0 = wid * 512 + t * 64;

    // stage dist tile [16 rows x 64 cols] -> dbuf (one instruction)
    gload_lds16(dist + (size_t)(qr0 + (lane >> 2)) * 2048 + kv0 + (lane & 3) * 16, dbuf);

    // --- S = Q K^T ---
    f32x4 sacc[4] = {};
    #pragma unroll
    for (int nt = 0; nt < 4; ++nt)
      #pragma unroll
      for (int ks = 0; ks < 2; ++ks) {
        short8 bk = *(const short8*)(km + (size_t)(kv0 + nt * 16 + c15) * 512 + h * 64 + ks * 32 + g * 8);
        sacc[nt] = __builtin_amdgcn_mfma_f32_16x16x32_bf16(aq[ks], bk, sacc[nt], 0, 0, 0);
      }

    // dist tile staged? (gload_lds completion is vmcnt; compiler can't track)
    asm volatile("s_waitcnt vmcnt(0)" ::: "memory");
    __builtin_amdgcn_sched_barrier(0);

    // --- scale + spatial bias; row stats ---
    float sv[4][4];
    float rmax[4];
    #pragma unroll
    for (int r = 0; r < 4; ++r) rmax[r] = -1e30f;
    #pragma unroll
    for (int nt = 0; nt < 4; ++nt)
      #pragma unroll
      for (int r = 0; r < 4; ++r) {
        float b = semb_s[dbuf[(g * 4 + r) * 64 + nt * 16 + c15]];
        float s = sacc[nt][r] * 0.125f + b;
        sv[nt][r] = s;
        rmax[r] = fmaxf(rmax[r], s);
      }
    #pragma unroll
    for (int r = 0; r < 4; ++r) {
      rmax[r] = fmaxf(rmax[r], __shfl_xor(rmax[r], 1));
      rmax[r] = fmaxf(rmax[r], __shfl_xor(rmax[r], 2));
      rmax[r] = fmaxf(rmax[r], __shfl_xor(rmax[r], 4));
      rmax[r] = fmaxf(rmax[r], __shfl_xor(rmax[r], 8));
    }

    // --- online softmax update ---
    float pscale[4], rsum[4];
    #pragma unroll
    for (int r = 0; r < 4; ++r) {
      float mn = fmaxf(m[r], rmax[r]);
      pscale[r] = __expf(m[r] - mn);
      m[r] = mn;
      rsum[r] = 0.0f;
    }
    #pragma unroll
    for (int nt = 0; nt < 4; ++nt)
      #pragma unroll
      for (int r = 0; r < 4; ++r) {
        float p = __expf(sv[nt][r] - m[r]);
        sv[nt][r] = p;
        rsum[r] += p;
      }
    #pragma unroll
    for (int r = 0; r < 4; ++r) {
      rsum[r] += __shfl_xor(rsum[r], 1);
      rsum[r] += __shfl_xor(rsum[r], 2);
      rsum[r] += __shfl_xor(rsum[r], 4);
      rsum[r] += __shfl_xor(rsum[r], 8);
      l[r] = l[r] * pscale[r] + rsum[r];
    }
    #pragma unroll
    for (int dt = 0; dt < 4; ++dt)
      #pragma unroll
      for (int r = 0; r < 4; ++r)
        o[dt][r] *= pscale[r];

    // --- P -> bf16, transpose via LDS (swizzle: byte ^= (q&3)<<5) ---
    #pragma unroll
    for (int nt = 0; nt < 4; ++nt)
      #pragma unroll
      for (int r = 0; r < 4; ++r) {
        int qloc = g * 4 + r;
        int colb = (nt * 16 + c15) * 2;
        int addr = qloc * 128 + (colb ^ ((qloc & 3) << 5));
        *(unsigned short*)(pbuf + addr) = f2bf(sv[nt][r]);
      }
    short8 pa[2];
    #pragma unroll
    for (int ks = 0; ks < 2; ++ks) {
      int chunk = (ks * 4 + g) ^ ((c15 & 3) << 1);
      pa[ks] = *(const short8*)(pbuf + c15 * 128 + chunk * 16);
    }

    // --- O += P V ---
    #pragma unroll
    for (int dt = 0; dt < 4; ++dt)
      #pragma unroll
      for (int ks = 0; ks < 2; ++ks) {
        short8 bv = *(const short8*)(vT + (size_t)(h * 64 + dt * 16 + c15) * 2048 + kv0 + ks * 32 + g * 8);
        o[dt] = __builtin_amdgcn_mfma_f32_16x16x32_bf16(pa[ks], bv, o[dt], 0, 0, 0);
      }
  }

  // ---- combine per-wave partials via LDS ----
  __syncthreads();                    // all waves done with pbuf/dbuf
  float* o_s  = (float*)lds;          // [16 dtr][256 = w*64+lane]
  float* ml_s = (float*)(lds + 16384);// [w][16 rows][2]
  #pragma unroll
  for (int dt = 0; dt < 4; ++dt)
    #pragma unroll
    for (int r = 0; r < 4; ++r)
      o_s[(dt * 4 + r) * 256 + wid * 64 + lane] = o[dt][r];
  if (c15 == 0) {
    #pragma unroll
    for (int r = 0; r < 4; ++r) {
      ml_s[wid * 32 + (g * 4 + r) * 2]     = m[r];
      ml_s[wid * 32 + (g * 4 + r) * 2 + 1] = l[r];
    }
  }
  __syncthreads();

  if (wid == 0) {
    float e[4][4], lsum[4];
    #pragma unroll
    for (int r = 0; r < 4; ++r) {
      int row = g * 4 + r;
      float m0 = ml_s[row * 2], m1 = ml_s[32 + row * 2],
            m2 = ml_s[64 + row * 2], m3 = ml_s[96 + row * 2];
      float ms = fmaxf(fmaxf(m0, m1), fmaxf(m2, m3));
      e[0][r] = __expf(m0 - ms); e[1][r] = __expf(m1 - ms);
      e[2][r] = __expf(m2 - ms); e[3][r] = __expf(m3 - ms);
      lsum[r] = ml_s[row * 2 + 1] * e[0][r] + ml_s[32 + row * 2 + 1] * e[1][r] +
                ml_s[64 + row * 2 + 1] * e[2][r] + ml_s[96 + row * 2 + 1] * e[3][r];
    }
    #pragma unroll
    for (int dt = 0; dt < 4; ++dt)
      #pragma unroll
      for (int r = 0; r < 4; ++r) {
        float comb = 0.0f;
        #pragma unroll
        for (int w = 0; w < 4; ++w)
          comb += o_s[(dt * 4 + r) * 256 + w * 64 + lane] * e[w][r];
        int q = qr0 + g * 4 + r;
        ctx[(size_t)q * 512 + h * 64 + dt * 16 + c15] = f2bf(comb / lsum[r]);
      }
  }
}

// ---------------------------------------------------------------------------
// LayerNorm(a + b) row-wise; optional bf16 copy of the output
// ---------------------------------------------------------------------------
template <bool WB>
__global__ __launch_bounds__(256) void ln_kernel(
    const float* __restrict__ a, const float* __restrict__ b,
    const float* __restrict__ w, const float* __restrict__ bb,
    float* __restrict__ out, unsigned short* __restrict__ outb) {
  int row = blockIdx.x, tid = threadIdx.x;
  const float* ar = a + (size_t)row * 512;
  const float* br = b + (size_t)row * 512;
  float v0 = ar[tid] + br[tid];
  float v1 = ar[tid + 256] + br[tid + 256];
  float s = v0 + v1, q = v0 * v0 + v1 * v1;
  for (int o = 32; o > 0; o >>= 1) { s += __shfl_down(s, o); q += __shfl_down(q, o); }
  __shared__ float rs[4], rq[4], bc[2];
  int wid = tid >> 6, lane = tid & 63;
  if (lane == 0) { rs[wid] = s; rq[wid] = q; }
  __syncthreads();
  if (tid == 0) {
    float S = rs[0] + rs[1] + rs[2] + rs[3];
    float Q = rq[0] + rq[1] + rq[2] + rq[3];
    float mu = S * (1.0f / 512.0f);
    bc[0] = mu;
    bc[1] = Q * (1.0f / 512.0f) - mu * mu;
  }
  __syncthreads();
  float mu = bc[0], inv = rsqrtf(bc[1] + 1e-5f);
  float o0 = (v0 - mu) * inv * w[tid] + bb[tid];
  float o1 = (v1 - mu) * inv * w[tid + 256] + bb[tid + 256];
  out[(size_t)row * 512 + tid] = o0;
  out[(size_t)row * 512 + tid + 256] = o1;
  if (WB) {
    outb[(size_t)row * 512 + tid] = f2bf(o0);
    outb[(size_t)row * 512 + tid + 256] = f2bf(o1);
  }
}

// ---------------------------------------------------------------------------
extern "C" void kernel_launch(void* const* d_in, const int* in_sizes, int n_in,
                              void* d_out, int out_size, void* d_ws, size_t ws_size,
                              hipStream_t stream) {
  (void)in_sizes; (void)n_in; (void)out_size; (void)ws_size;
  const float* x    = (const float*)d_in[0];
  const float* adj  = (const float*)d_in[1];
  const float* semb = (const float*)d_in[2];
  const float* wq   = (const float*)d_in[3];
  const float* bq   = (const float*)d_in[4];
  const float* wk   = (const float*)d_in[5];
  const float* bk   = (const float*)d_in[6];
  const float* wv   = (const float*)d_in[7];
  const float* bv   = (const float*)d_in[8];
  const float* wo   = (const float*)d_in[9];
  const float* bo   = (const float*)d_in[10];
  const float* ln1w = (const float*)d_in[11];
  const float* ln1b = (const float*)d_in[12];
  const float* w1   = (const float*)d_in[13];
  const float* b1   = (const float*)d_in[14];
  const float* w2   = (const float*)d_in[15];
  const float* b2   = (const float*)d_in[16];
  const float* ln2w = (const float*)d_in[17];
  const float* ln2b = (const float*)d_in[18];
  float* out = (float*)d_out;
  char* ws = (char*)d_ws;

  uint32_t*       adjb = (uint32_t*)(ws + OFF_ADJB);
  uint8_t*        dist = (uint8_t*)(ws + OFF_DIST);
  unsigned short* xb   = (unsigned short*)(ws + OFF_XB);
  unsigned short* wqb  = (unsigned short*)(ws + OFF_WQB);
  unsigned short* wkb  = (unsigned short*)(ws + OFF_WKB);
  unsigned short* wvb  = (unsigned short*)(ws + OFF_WVB);
  unsigned short* wob  = (unsigned short*)(ws + OFF_WOB);
  unsigned short* w1b  = (unsigned short*)(ws + OFF_W1B);
  unsigned short* w2b  = (unsigned short*)(ws + OFF_W2B);
  unsigned short* qm   = (unsigned short*)(ws + OFF_QM);
  unsigned short* km   = (unsigned short*)(ws + OFF_KM);
  unsigned short* vT   = (unsigned short*)(ws + OFF_VT);
  unsigned short* ctx  = (unsigned short*)(ws + OFF_CTX);
  float*          atmp = (float*)(ws + OFF_ATMP);
  float*          h1   = (float*)(ws + OFF_H1);
  unsigned short* h1b  = (unsigned short*)(ws + OFF_H1B);
  unsigned short* mid  = (unsigned short*)(ws + OFF_MID);
  float*          ffn2 = (float*)(ws + OFF_FFN2);

  // ---- dtype conversions (fused) ----
  cvt_all_kernel<<<4096, 256, 0, stream>>>(x, wq, wk, wv, wo, w1, w2,
                                           xb, wqb, wkb, wvb, wob, w1b, w2b);

  // ---- spatial distances ----
  pack_adj_kernel<<<2048, 256, 0, stream>>>(adj, adjb);
  bfs_kernel<<<2048, 256, 0, stream>>>(adjb, dist);

  // ---- QKV projection (q,k row-major; v transposed) ----
  gemm_kernel<0><<<dim3(16, 12), 256, 0, stream>>>(
      (const short*)xb, (const short*)wqb, (const short*)wkb, (const short*)wvb,
      bq, bk, bv, qm, km, vT, nullptr, nullptr, 512, 512);

  // ---- attention ----
  attn_kernel<<<dim3(128, 8), 256, 0, stream>>>(
      (const short*)qm, (const short*)km, (const short*)vT, dist, semb, ctx);

  // ---- output projection ----
  gemm_kernel<1><<<dim3(16, 4), 256, 0, stream>>>(
      (const short*)ctx, (const short*)wob, nullptr, nullptr,
      bo, nullptr, nullptr, nullptr, nullptr, nullptr, atmp, nullptr, 512, 512);

  // ---- LN1 (x + attn_out) ----
  ln_kernel<true><<<2048, 256, 0, stream>>>(x, atmp, ln1w, ln1b, h1, h1b);

  // ---- FFN ----
  gemm_kernel<2><<<dim3(16, 16), 256, 0, stream>>>(
      (const short*)h1b, (const short*)w1b, nullptr, nullptr,
      b1, nullptr, nullptr, nullptr, nullptr, nullptr, nullptr, mid, 512, 2048);
  gemm_kernel<1><<<dim3(16, 4), 256, 0, stream>>>(
      (const short*)mid, (const short*)w2b, nullptr, nullptr,
      b2, nullptr, nullptr, nullptr, nullptr, nullptr, ffn2, nullptr, 2048, 512);

  // ---- LN2 (h1 + ffn) -> output ----
  ln_kernel<false><<<2048, 256, 0, stream>>>(h1, ffn2, ln2w, ln2b, out, nullptr);
}

// Round 4
// 217.242 us; speedup vs baseline: 2.1648x; 1.1981x over previous
//
#include <hip/hip_runtime.h>
#include <cstdint>
#include <cstddef>

// ---------------------------------------------------------------------------
// GraphTransformerLayer on MI355X (gfx950)
//  - Floyd-Warshall w/ clip(10)  ==  BFS truncated at depth 9 (bitset)
//    R3: gather vectorized to dwordx4 (4 adj rows / instruction), padded list
//  - QKV / out-proj / FFN GEMMs: bf16 MFMA 16x16x32, 128x128x64 tile, 2-phase,
//    global_load_lds(16B) with pre-swizzled global source (linear LDS dest)
//  - Attention: block = 16 q-rows x 1 head, 4 waves each own a 512-col KV
//    range (independent online softmax), LDS combine at end.
// ---------------------------------------------------------------------------

typedef __attribute__((ext_vector_type(8))) short short8;     // 8 x bf16 (4 VGPR)
typedef __attribute__((ext_vector_type(4))) float f32x4;      // MFMA C/D frag

#define N_NODES 2048
#define DMODEL  512
#define NHEAD   8
#define DHEAD   64
#define FFDIM   2048

// ---- workspace layout (bytes) ---------------------------------------------
#define OFF_ADJB   (0)                       // u32 [2048][64]        512 KB
#define OFF_DIST   (0x80000)                 // u8  [2048][2048]      4 MB
#define OFF_XB     (0x480000)                // bf16[2048][512]       2 MB
#define OFF_WQB    (0x680000)                // bf16[512][512]        512 KB
#define OFF_WKB    (0x700000)
#define OFF_WVB    (0x780000)
#define OFF_WOB    (0x800000)
#define OFF_W1B    (0x880000)                // bf16[2048][512]       2 MB
#define OFF_W2B    (0xA80000)                // bf16[512][2048]       2 MB
#define OFF_QM     (0xC80000)                // bf16[2048][512]       2 MB
#define OFF_KM     (0xE80000)                // bf16[2048][512]       2 MB
#define OFF_VT     (0x1080000)               // bf16[512][2048]       2 MB (vT[d][n])
#define OFF_CTX    (0x1280000)               // bf16[2048][512]       2 MB
#define OFF_ATMP   (0x1480000)               // f32 [2048][512]       4 MB
#define OFF_H1     (0x1880000)               // f32 [2048][512]       4 MB
#define OFF_H1B    (0x1C80000)               // bf16[2048][512]       2 MB
#define OFF_MID    (0x1E80000)               // bf16[2048][2048]      8 MB
#define OFF_FFN2   (0x2680000)               // f32 [2048][512]       4 MB
// total 44.5 MB

__device__ __forceinline__ unsigned short f2bf(float f) {
  union { float f; unsigned u; } c; c.f = f;
  unsigned r = c.u + 0x7FFFu + ((c.u >> 16) & 1u);   // RNE
  return (unsigned short)(r >> 16);
}

// global -> LDS async, 16B per lane. HW writes LDS at wave-uniform base + lane*16.
typedef const __attribute__((address_space(1))) unsigned int* as1_u32p;
typedef __attribute__((address_space(3))) unsigned int* as3_u32p;
__device__ __forceinline__ void gload_lds16(const void* g, void* l) {
  __builtin_amdgcn_global_load_lds((as1_u32p)g, (as3_u32p)l, 16, 0, 0);
}

// ---------------------------------------------------------------------------
// fused f32 -> bf16 conversion for all 7 arrays (4 elems/thread)
// ---------------------------------------------------------------------------
__global__ void cvt_all_kernel(const float* __restrict__ x,
                               const float* __restrict__ wq, const float* __restrict__ wk,
                               const float* __restrict__ wv, const float* __restrict__ wo,
                               const float* __restrict__ w1, const float* __restrict__ w2,
                               unsigned short* __restrict__ xb,
                               unsigned short* __restrict__ wqb, unsigned short* __restrict__ wkb,
                               unsigned short* __restrict__ wvb, unsigned short* __restrict__ wob,
                               unsigned short* __restrict__ w1b, unsigned short* __restrict__ w2b) {
  int i = blockIdx.x * 256 + threadIdx.x;       // 0 .. 1048575
  const float* src; unsigned short* dst; int off;
  if (i < 262144)      { src = x;  dst = xb;  off = i; }
  else if (i < 327680) { src = wq; dst = wqb; off = i - 262144; }
  else if (i < 393216) { src = wk; dst = wkb; off = i - 327680; }
  else if (i < 458752) { src = wv; dst = wvb; off = i - 393216; }
  else if (i < 524288) { src = wo; dst = wob; off = i - 458752; }
  else if (i < 786432) { src = w1; dst = w1b; off = i - 524288; }
  else                 { src = w2; dst = w2b; off = i - 786432; }
  float4 v = ((const float4*)src)[off];
  unsigned p0 = (unsigned)f2bf(v.x) | ((unsigned)f2bf(v.y) << 16);
  unsigned p1 = (unsigned)f2bf(v.z) | ((unsigned)f2bf(v.w) << 16);
  ((uint2*)dst)[off] = make_uint2(p0, p1);
}

// ---------------------------------------------------------------------------
// adj (f32 0/1) -> row bitsets, u32 [2048][64]
// ---------------------------------------------------------------------------
__global__ void pack_adj_kernel(const float* __restrict__ adj, uint32_t* __restrict__ adjb) {
  int i = blockIdx.x;
  int tid = threadIdx.x, wid = tid >> 6, lane = tid & 63;
  for (int it = 0; it < 8; ++it) {
    int jbase = it * 256 + wid * 64;
    int j = jbase + lane;
    unsigned long long m = __ballot(adj[(size_t)i * 2048 + j] > 0.0f);
    int w32 = jbase >> 5;
    if (lane == 0)  adjb[i * 64 + w32]     = (uint32_t)m;
    if (lane == 32) adjb[i * 64 + w32 + 1] = (uint32_t)(m >> 32);
  }
}

// ---------------------------------------------------------------------------
// BFS truncated at depth 9 -> dist u8 in [0,10].
// One block (4 waves) per source row. Per level: compact frontier into LDS
// list (popcount + shfl scan), pad to x64 with the source id (its row is a
// subset of reach -> redundant OR is harmless), then gather with dwordx4:
// lane l loads words [(l&15)*4,+4) of node list[base + j*4 + (l>>4)] -- one
// instruction covers 4 full adj rows; 4-deep ILP -> 16 nodes/wave/iter.
// ---------------------------------------------------------------------------
__global__ __launch_bounds__(256) void bfs_kernel(const uint32_t* __restrict__ adjb,
                                                  uint8_t* __restrict__ dist) {
  int i = blockIdx.x;
  int tid = threadIdx.x, wid = tid >> 6, lane = tid & 63;

  __shared__ uint16_t list_s[2112];
  __shared__ uint4 comb_v[4][64];
  __shared__ uint32_t wtot[4];
  const uint32_t* comb_u = (const uint32_t*)comb_v;

  uint32_t adjrow = adjb[i * 64 + lane];
  uint32_t diagm  = (lane == (i >> 5)) ? (1u << (i & 31)) : 0u;
  uint32_t front  = adjrow & ~diagm;          // exactly distance-1 nodes
  uint32_t reach  = front | diagm;
  uint32_t dp0 = front;
  uint32_t dp1 = ~(front | diagm);
  uint32_t dp2 = 0u;
  uint32_t dp3 = dp1;

  for (int t = 2; t <= 9; ++t) {
    // --- compact frontier into list_s ---
    uint32_t fw = __shfl(front, wid * 16 + (lane >> 2));
    uint32_t fb = (fw >> ((lane & 3) * 8)) & 0xFFu;
    int cnt = __popc(fb);
    int scan = cnt;                          // wave-inclusive scan
    #pragma unroll
    for (int o = 1; o < 64; o <<= 1) {
      int u = __shfl_up(scan, o);
      if (lane >= o) scan += u;
    }
    if (lane == 63) wtot[wid] = (uint32_t)scan;
    __syncthreads();
    int w0 = (int)wtot[0], w1 = (int)wtot[1], w2 = (int)wtot[2], w3 = (int)wtot[3];
    int cnt_total = w0 + w1 + w2 + w3;
    if (cnt_total == 0) break;
    int base0 = (wid > 0 ? w0 : 0) + (wid > 1 ? w1 : 0) + (wid > 2 ? w2 : 0);
    int off = base0 + scan - cnt;            // exclusive offset for this thread
    int nodebase = tid * 8;
    while (fb) {
      int b = __builtin_ctz(fb);
      fb &= fb - 1u;
      list_s[off++] = (uint16_t)(nodebase + b);
    }
    int padded = (cnt_total + 63) & ~63;
    for (int k = cnt_total + tid; k < padded; k += 256)
      list_s[k] = (uint16_t)i;               // source row: subset of reach
    __syncthreads();

    // --- gather: dwordx4, 4 nodes per load, 4 loads in flight ---
    uint4 acc = make_uint4(0u, 0u, 0u, 0u);
    int wsub = (lane & 15) * 4;              // this lane's word range
    for (int base = wid * 16; base < padded; base += 64) {
      #pragma unroll
      for (int j = 0; j < 4; ++j) {
        int node = list_s[base + j * 4 + (lane >> 4)];
        uint4 v = *(const uint4*)(adjb + node * 64 + wsub);
        acc.x |= v.x; acc.y |= v.y; acc.z |= v.z; acc.w |= v.w;
      }
    }
    comb_v[wid][lane] = acc;
    __syncthreads();
    // word `lane` = OR over waves w4 and node-groups g of
    //   comb_u[w4*256 + g*64 + (lane>>2)*4 + (lane&3)]  (lane-consecutive)
    uint32_t orv = 0;
    int idx = (lane >> 2) * 4 + (lane & 3);
    #pragma unroll
    for (int w4 = 0; w4 < 4; ++w4)
      #pragma unroll
      for (int g = 0; g < 4; ++g)
        orv |= comb_u[w4 * 256 + g * 64 + idx];
    uint32_t nreach = reach | orv;
    uint32_t nf = nreach & ~reach;
    dp0 = (dp0 & ~nf) | ((t & 1) ? nf : 0u);
    dp1 = (dp1 & ~nf) | ((t & 2) ? nf : 0u);
    dp2 = (dp2 & ~nf) | ((t & 4) ? nf : 0u);
    dp3 = (dp3 & ~nf) | ((t & 8) ? nf : 0u);
    front = nf;
    reach = nreach;
    __syncthreads();                         // protect list_s/comb for next level
  }

  uint32_t p0 = __shfl(dp0, wid * 16 + (lane >> 2));
  uint32_t p1 = __shfl(dp1, wid * 16 + (lane >> 2));
  uint32_t p2 = __shfl(dp2, wid * 16 + (lane >> 2));
  uint32_t p3 = __shfl(dp3, wid * 16 + (lane >> 2));
  int sh = (lane & 3) * 8;
  uint32_t lo = 0, hi = 0;
  #pragma unroll
  for (int j = 0; j < 4; ++j) {
    int bit = sh + j;
    uint32_t d = ((p0 >> bit) & 1u) | (((p1 >> bit) & 1u) << 1) |
                 (((p2 >> bit) & 1u) << 2) | (((p3 >> bit) & 1u) << 3);
    lo |= d << (8 * j);
  }
  #pragma unroll
  for (int j = 0; j < 4; ++j) {
    int bit = sh + 4 + j;
    uint32_t d = ((p0 >> bit) & 1u) | (((p1 >> bit) & 1u) << 1) |
                 (((p2 >> bit) & 1u) << 2) | (((p3 >> bit) & 1u) << 3);
    hi |= d << (8 * j);
  }
  ((uint2*)(dist + (size_t)i * 2048))[tid] = make_uint2(lo, hi);
}

// ---------------------------------------------------------------------------
// GEMM core: C[128,128] += A[128,K] * W[128,K]^T   (both bf16 row-major, ld = K)
// ---------------------------------------------------------------------------
__device__ __forceinline__ void gemm_core(const short* __restrict__ A,
                                          const short* __restrict__ W,
                                          int K, int am0, int bn0,
                                          f32x4 acc[4][4], char* smem) {
  int tid = threadIdx.x, wid = tid >> 6, lane = tid & 63;
  int c15 = lane & 15, g = lane >> 4;
  int wm = wid >> 1, wn = wid & 1;
  char* As = smem;
  char* Bs = smem + 16384;

  for (int kt = 0; kt < K; kt += 64) {
    __syncthreads();   // previous tile's LDS reads done
    #pragma unroll
    for (int i = 0; i < 4; ++i) {
      int c   = i * 256 + tid;
      int row = c >> 3;
      int kg  = (c & 7) ^ (row & 7);
      gload_lds16(A + (size_t)(am0 + row) * K + kt + kg * 8,
                  As + i * 4096 + wid * 1024);
      gload_lds16(W + (size_t)(bn0 + row) * K + kt + kg * 8,
                  Bs + i * 4096 + wid * 1024);
    }
    __syncthreads();   // staging complete (implicit vmcnt(0))
    #pragma unroll
    for (int ks = 0; ks < 2; ++ks) {
      short8 af[4], bfr[4];
      #pragma unroll
      for (int mt = 0; mt < 4; ++mt) {
        int row   = wm * 64 + mt * 16 + c15;
        int chunk = (ks * 4 + g) ^ (row & 7);
        af[mt] = *(const short8*)(As + row * 128 + chunk * 16);
      }
      #pragma unroll
      for (int nt = 0; nt < 4; ++nt) {
        int row   = wn * 64 + nt * 16 + c15;
        int chunk = (ks * 4 + g) ^ (row & 7);
        bfr[nt] = *(const short8*)(Bs + row * 128 + chunk * 16);
      }
      #pragma unroll
      for (int mt = 0; mt < 4; ++mt)
        #pragma unroll
        for (int nt = 0; nt < 4; ++nt)
          acc[mt][nt] = __builtin_amdgcn_mfma_f32_16x16x32_bf16(af[mt], bfr[nt], acc[mt][nt], 0, 0, 0);
    }
  }
}

// MODE 0: QKV (3 weight regions; q,k -> bf16 row-major; v -> bf16 transposed vT[d][n])
// MODE 1: f32 out + bias
// MODE 2: bf16 out + bias + exact GELU
template <int MODE>
__global__ __launch_bounds__(256) void gemm_kernel(
    const short* __restrict__ A,
    const short* __restrict__ W0, const short* __restrict__ W1, const short* __restrict__ W2,
    const float* __restrict__ b0, const float* __restrict__ b1, const float* __restrict__ b2,
    unsigned short* __restrict__ outq, unsigned short* __restrict__ outk, unsigned short* __restrict__ outv,
    float* __restrict__ outf, unsigned short* __restrict__ outb,
    int K, int ldo) {
  __shared__ __align__(16) char smem[32768];
  int by = blockIdx.y;
  const short* W; const float* bias; int bn0;
  int region = 0;
  if (MODE == 0) {
    region = by >> 2;
    W    = (region == 0) ? W0 : (region == 1) ? W1 : W2;
    bias = (region == 0) ? b0 : (region == 1) ? b1 : b2;
    bn0  = (by & 3) * 128;
  } else {
    W = W0; bias = b0; bn0 = by * 128;
  }
  int am0 = blockIdx.x * 128;

  f32x4 acc[4][4] = {};
  gemm_core(A, W, K, am0, bn0, acc, smem);

  int tid = threadIdx.x, wid = tid >> 6, lane = tid & 63;
  int c15 = lane & 15, g = lane >> 4;
  int wm = wid >> 1, wn = wid & 1;

  #pragma unroll
  for (int mt = 0; mt < 4; ++mt)
    #pragma unroll
    for (int nt = 0; nt < 4; ++nt)
      #pragma unroll
      for (int r = 0; r < 4; ++r) {
        int row = am0 + wm * 64 + mt * 16 + g * 4 + r;   // D: row=(lane>>4)*4+reg
        int col = bn0 + wn * 64 + nt * 16 + c15;         // D: col=lane&15
        float v = acc[mt][nt][r] + bias[col];
        if (MODE == 0) {
          if (region == 0)      outq[(size_t)row * 512 + col] = f2bf(v);
          else if (region == 1) outk[(size_t)row * 512 + col] = f2bf(v);
          else                  outv[(size_t)col * 2048 + row] = f2bf(v);   // vT[d][n]
        } else if (MODE == 1) {
          outf[(size_t)row * ldo + col] = v;
        } else {
          float gv = 0.5f * v * (1.0f + erff(v * 0.70710678118654752f));
          outb[(size_t)row * ldo + col] = f2bf(gv);
        }
      }
}

// ---------------------------------------------------------------------------
// Flash attention.
// Block (qt, h): q rows [qt*16, +16) of head h. 4 waves; wave w owns KV cols
// [w*512, +512) with an independent online softmax; partials (m,l,O) combined
// via LDS at the end. dist tiles (16x64 u8) staged by one global_load_lds.
// ---------------------------------------------------------------------------
__global__ __launch_bounds__(256, 4) void attn_kernel(
    const short* __restrict__ qm, const short* __restrict__ km,
    const short* __restrict__ vT, const uint8_t* __restrict__ dist,
    const float* __restrict__ semb, unsigned short* __restrict__ ctx) {
  int qt = blockIdx.x, h = blockIdx.y;
  int tid = threadIdx.x, wid = tid >> 6, lane = tid & 63;
  int c15 = lane & 15, g = lane >> 4;

  __shared__ __align__(16) char lds[16896];
  __shared__ float semb_s[12];
  if (tid < 11) semb_s[tid] = semb[tid];
  __syncthreads();

  char* pbuf = lds + wid * 2048;
  uint8_t* dbuf = (uint8_t*)(lds + 8192 + wid * 1024);

  int qr0 = qt * 16;

  short8 aq[2];
  #pragma unroll
  for (int ks = 0; ks < 2; ++ks)
    aq[ks] = *(const short8*)(qm + (size_t)(qr0 + c15) * 512 + h * 64 + ks * 32 + g * 8);

  f32x4 o[4] = {};
  float m[4], l[4];
  #pragma unroll
  for (int r = 0; r < 4; ++r) { m[r] = -1e30f; l[r] = 0.0f; }

  for (int t = 0; t < 8; ++t) {
    int kv0 = wid * 512 + t * 64;

    // stage dist tile [16 rows x 64 cols] -> dbuf (one instruction)
    gload_lds16(dist + (size_t)(qr0 + (lane >> 2)) * 2048 + kv0 + (lane & 3) * 16, dbuf);

    // --- S = Q K^T ---
    f32x4 sacc[4] = {};
    #pragma unroll
    for (int nt = 0; nt < 4; ++nt)
      #pragma unroll
      for (int ks = 0; ks < 2; ++ks) {
        short8 bk = *(const short8*)(km + (size_t)(kv0 + nt * 16 + c15) * 512 + h * 64 + ks * 32 + g * 8);
        sacc[nt] = __builtin_amdgcn_mfma_f32_16x16x32_bf16(aq[ks], bk, sacc[nt], 0, 0, 0);
      }

    // dist tile staged? (gload_lds completion is vmcnt; compiler can't track)
    asm volatile("s_waitcnt vmcnt(0)" ::: "memory");
    __builtin_amdgcn_sched_barrier(0);

    // --- scale + spatial bias; row stats ---
    float sv[4][4];
    float rmax[4];
    #pragma unroll
    for (int r = 0; r < 4; ++r) rmax[r] = -1e30f;
    #pragma unroll
    for (int nt = 0; nt < 4; ++nt)
      #pragma unroll
      for (int r = 0; r < 4; ++r) {
        float b = semb_s[dbuf[(g * 4 + r) * 64 + nt * 16 + c15]];
        float s = sacc[nt][r] * 0.125f + b;
        sv[nt][r] = s;
        rmax[r] = fmaxf(rmax[r], s);
      }
    #pragma unroll
    for (int r = 0; r < 4; ++r) {
      rmax[r] = fmaxf(rmax[r], __shfl_xor(rmax[r], 1));
      rmax[r] = fmaxf(rmax[r], __shfl_xor(rmax[r], 2));
      rmax[r] = fmaxf(rmax[r], __shfl_xor(rmax[r], 4));
      rmax[r] = fmaxf(rmax[r], __shfl_xor(rmax[r], 8));
    }

    // --- online softmax update ---
    float pscale[4], rsum[4];
    #pragma unroll
    for (int r = 0; r < 4; ++r) {
      float mn = fmaxf(m[r], rmax[r]);
      pscale[r] = __expf(m[r] - mn);
      m[r] = mn;
      rsum[r] = 0.0f;
    }
    #pragma unroll
    for (int nt = 0; nt < 4; ++nt)
      #pragma unroll
      for (int r = 0; r < 4; ++r) {
        float p = __expf(sv[nt][r] - m[r]);
        sv[nt][r] = p;
        rsum[r] += p;
      }
    #pragma unroll
    for (int r = 0; r < 4; ++r) {
      rsum[r] += __shfl_xor(rsum[r], 1);
      rsum[r] += __shfl_xor(rsum[r], 2);
      rsum[r] += __shfl_xor(rsum[r], 4);
      rsum[r] += __shfl_xor(rsum[r], 8);
      l[r] = l[r] * pscale[r] + rsum[r];
    }
    #pragma unroll
    for (int dt = 0; dt < 4; ++dt)
      #pragma unroll
      for (int r = 0; r < 4; ++r)
        o[dt][r] *= pscale[r];

    // --- P -> bf16, transpose via LDS (swizzle: byte ^= (q&3)<<5) ---
    #pragma unroll
    for (int nt = 0; nt < 4; ++nt)
      #pragma unroll
      for (int r = 0; r < 4; ++r) {
        int qloc = g * 4 + r;
        int colb = (nt * 16 + c15) * 2;
        int addr = qloc * 128 + (colb ^ ((qloc & 3) << 5));
        *(unsigned short*)(pbuf + addr) = f2bf(sv[nt][r]);
      }
    short8 pa[2];
    #pragma unroll
    for (int ks = 0; ks < 2; ++ks) {
      int chunk = (ks * 4 + g) ^ ((c15 & 3) << 1);
      pa[ks] = *(const short8*)(pbuf + c15 * 128 + chunk * 16);
    }

    // --- O += P V ---
    #pragma unroll
    for (int dt = 0; dt < 4; ++dt)
      #pragma unroll
      for (int ks = 0; ks < 2; ++ks) {
        short8 bv = *(const short8*)(vT + (size_t)(h * 64 + dt * 16 + c15) * 2048 + kv0 + ks * 32 + g * 8);
        o[dt] = __builtin_amdgcn_mfma_f32_16x16x32_bf16(pa[ks], bv, o[dt], 0, 0, 0);
      }
  }

  // ---- combine per-wave partials via LDS ----
  __syncthreads();                    // all waves done with pbuf/dbuf
  float* o_s  = (float*)lds;          // [16 dtr][256 = w*64+lane]
  float* ml_s = (float*)(lds + 16384);// [w][16 rows][2]
  #pragma unroll
  for (int dt = 0; dt < 4; ++dt)
    #pragma unroll
    for (int r = 0; r < 4; ++r)
      o_s[(dt * 4 + r) * 256 + wid * 64 + lane] = o[dt][r];
  if (c15 == 0) {
    #pragma unroll
    for (int r = 0; r < 4; ++r) {
      ml_s[wid * 32 + (g * 4 + r) * 2]     = m[r];
      ml_s[wid * 32 + (g * 4 + r) * 2 + 1] = l[r];
    }
  }
  __syncthreads();

  if (wid == 0) {
    float e[4][4], lsum[4];
    #pragma unroll
    for (int r = 0; r < 4; ++r) {
      int row = g * 4 + r;
      float m0 = ml_s[row * 2], m1 = ml_s[32 + row * 2],
            m2 = ml_s[64 + row * 2], m3 = ml_s[96 + row * 2];
      float ms = fmaxf(fmaxf(m0, m1), fmaxf(m2, m3));
      e[0][r] = __expf(m0 - ms); e[1][r] = __expf(m1 - ms);
      e[2][r] = __expf(m2 - ms); e[3][r] = __expf(m3 - ms);
      lsum[r] = ml_s[row * 2 + 1] * e[0][r] + ml_s[32 + row * 2 + 1] * e[1][r] +
                ml_s[64 + row * 2 + 1] * e[2][r] + ml_s[96 + row * 2 + 1] * e[3][r];
    }
    #pragma unroll
    for (int dt = 0; dt < 4; ++dt)
      #pragma unroll
      for (int r = 0; r < 4; ++r) {
        float comb = 0.0f;
        #pragma unroll
        for (int w = 0; w < 4; ++w)
          comb += o_s[(dt * 4 + r) * 256 + w * 64 + lane] * e[w][r];
        int q = qr0 + g * 4 + r;
        ctx[(size_t)q * 512 + h * 64 + dt * 16 + c15] = f2bf(comb / lsum[r]);
      }
  }
}

// ---------------------------------------------------------------------------
// LayerNorm(a + b) row-wise; optional bf16 copy of the output
// ---------------------------------------------------------------------------
template <bool WB>
__global__ __launch_bounds__(256) void ln_kernel(
    const float* __restrict__ a, const float* __restrict__ b,
    const float* __restrict__ w, const float* __restrict__ bb,
    float* __restrict__ out, unsigned short* __restrict__ outb) {
  int row = blockIdx.x, tid = threadIdx.x;
  const float* ar = a + (size_t)row * 512;
  const float* br = b + (size_t)row * 512;
  float v0 = ar[tid] + br[tid];
  float v1 = ar[tid + 256] + br[tid + 256];
  float s = v0 + v1, q = v0 * v0 + v1 * v1;
  for (int o = 32; o > 0; o >>= 1) { s += __shfl_down(s, o); q += __shfl_down(q, o); }
  __shared__ float rs[4], rq[4], bc[2];
  int wid = tid >> 6, lane = tid & 63;
  if (lane == 0) { rs[wid] = s; rq[wid] = q; }
  __syncthreads();
  if (tid == 0) {
    float S = rs[0] + rs[1] + rs[2] + rs[3];
    float Q = rq[0] + rq[1] + rq[2] + rq[3];
    float mu = S * (1.0f / 512.0f);
    bc[0] = mu;
    bc[1] = Q * (1.0f / 512.0f) - mu * mu;
  }
  __syncthreads();
  float mu = bc[0], inv = rsqrtf(bc[1] + 1e-5f);
  float o0 = (v0 - mu) * inv * w[tid] + bb[tid];
  float o1 = (v1 - mu) * inv * w[tid + 256] + bb[tid + 256];
  out[(size_t)row * 512 + tid] = o0;
  out[(size_t)row * 512 + tid + 256] = o1;
  if (WB) {
    outb[(size_t)row * 512 + tid] = f2bf(o0);
    outb[(size_t)row * 512 + tid + 256] = f2bf(o1);
  }
}

// ---------------------------------------------------------------------------
extern "C" void kernel_launch(void* const* d_in, const int* in_sizes, int n_in,
                              void* d_out, int out_size, void* d_ws, size_t ws_size,
                              hipStream_t stream) {
  (void)in_sizes; (void)n_in; (void)out_size; (void)ws_size;
  const float* x    = (const float*)d_in[0];
  const float* adj  = (const float*)d_in[1];
  const float* semb = (const float*)d_in[2];
  const float* wq   = (const float*)d_in[3];
  const float* bq   = (const float*)d_in[4];
  const float* wk   = (const float*)d_in[5];
  const float* bk   = (const float*)d_in[6];
  const float* wv   = (const float*)d_in[7];
  const float* bv   = (const float*)d_in[8];
  const float* wo   = (const float*)d_in[9];
  const float* bo   = (const float*)d_in[10];
  const float* ln1w = (const float*)d_in[11];
  const float* ln1b = (const float*)d_in[12];
  const float* w1   = (const float*)d_in[13];
  const float* b1   = (const float*)d_in[14];
  const float* w2   = (const float*)d_in[15];
  const float* b2   = (const float*)d_in[16];
  const float* ln2w = (const float*)d_in[17];
  const float* ln2b = (const float*)d_in[18];
  float* out = (float*)d_out;
  char* ws = (char*)d_ws;

  uint32_t*       adjb = (uint32_t*)(ws + OFF_ADJB);
  uint8_t*        dist = (uint8_t*)(ws + OFF_DIST);
  unsigned short* xb   = (unsigned short*)(ws + OFF_XB);
  unsigned short* wqb  = (unsigned short*)(ws + OFF_WQB);
  unsigned short* wkb  = (unsigned short*)(ws + OFF_WKB);
  unsigned short* wvb  = (unsigned short*)(ws + OFF_WVB);
  unsigned short* wob  = (unsigned short*)(ws + OFF_WOB);
  unsigned short* w1b  = (unsigned short*)(ws + OFF_W1B);
  unsigned short* w2b  = (unsigned short*)(ws + OFF_W2B);
  unsigned short* qm   = (unsigned short*)(ws + OFF_QM);
  unsigned short* km   = (unsigned short*)(ws + OFF_KM);
  unsigned short* vT   = (unsigned short*)(ws + OFF_VT);
  unsigned short* ctx  = (unsigned short*)(ws + OFF_CTX);
  float*          atmp = (float*)(ws + OFF_ATMP);
  float*          h1   = (float*)(ws + OFF_H1);
  unsigned short* h1b  = (unsigned short*)(ws + OFF_H1B);
  unsigned short* mid  = (unsigned short*)(ws + OFF_MID);
  float*          ffn2 = (float*)(ws + OFF_FFN2);

  // ---- dtype conversions (fused) ----
  cvt_all_kernel<<<4096, 256, 0, stream>>>(x, wq, wk, wv, wo, w1, w2,
                                           xb, wqb, wkb, wvb, wob, w1b, w2b);

  // ---- spatial distances ----
  pack_adj_kernel<<<2048, 256, 0, stream>>>(adj, adjb);
  bfs_kernel<<<2048, 256, 0, stream>>>(adjb, dist);

  // ---- QKV projection (q,k row-major; v transposed) ----
  gemm_kernel<0><<<dim3(16, 12), 256, 0, stream>>>(
      (const short*)xb, (const short*)wqb, (const short*)wkb, (const short*)wvb,
      bq, bk, bv, qm, km, vT, nullptr, nullptr, 512, 512);

  // ---- attention ----
  attn_kernel<<<dim3(128, 8), 256, 0, stream>>>(
      (const short*)qm, (const short*)km, (const short*)vT, dist, semb, ctx);

  // ---- output projection ----
  gemm_kernel<1><<<dim3(16, 4), 256, 0, stream>>>(
      (const short*)ctx, (const short*)wob, nullptr, nullptr,
      bo, nullptr, nullptr, nullptr, nullptr, nullptr, atmp, nullptr, 512, 512);

  // ---- LN1 (x + attn_out) ----
  ln_kernel<true><<<2048, 256, 0, stream>>>(x, atmp, ln1w, ln1b, h1, h1b);

  // ---- FFN ----
  gemm_kernel<2><<<dim3(16, 16), 256, 0, stream>>>(
      (const short*)h1b, (const short*)w1b, nullptr, nullptr,
      b1, nullptr, nullptr, nullptr, nullptr, nullptr, nullptr, mid, 512, 2048);
  gemm_kernel<1><<<dim3(16, 4), 256, 0, stream>>>(
      (const short*)mid, (const short*)w2b, nullptr, nullptr,
      b2, nullptr, nullptr, nullptr, nullptr, nullptr, ffn2, nullptr, 2048, 512);

  // ---- LN2 (h1 + ffn) -> output ----
  ln_kernel<false><<<2048, 256, 0, stream>>>(h1, ffn2, ln2w, ln2b, out, nullptr);
}

// Round 5
// 176.151 us; speedup vs baseline: 2.6698x; 1.2333x over previous
//
#include <hip/hip_runtime.h>
#include <cstdint>
#include <cstddef>

// ---------------------------------------------------------------------------
// GraphTransformerLayer on MI355X (gfx950)
//  - Floyd-Warshall w/ clip(10)  ==  BFS truncated at depth 9 (bitset)
//  - GEMMs R5: 64x64 tiles (4x grid), split-K for N=512 GEMMs (partials summed
//    in the LN kernels -- deterministic, no atomics)
//  - Attention R5: KV-split x2 across blocks (2048 blocks = 8/CU = 100% occ),
//    unnormalized (m,l,O) partials + tiny combine kernel
// ---------------------------------------------------------------------------

typedef __attribute__((ext_vector_type(8))) short short8;     // 8 x bf16 (4 VGPR)
typedef __attribute__((ext_vector_type(4))) float f32x4;      // MFMA C/D frag

#define N_NODES 2048
#define DMODEL  512
#define NHEAD   8
#define DHEAD   64
#define FFDIM   2048

// ---- workspace layout (bytes) ---------------------------------------------
#define OFF_ADJB   (0)                       // u32 [2048][64]        512 KB
#define OFF_DIST   (0x80000)                 // u8  [2048][2048]      4 MB  (later: f32 partial x1)
#define OFF_XB     (0x480000)                // bf16[2048][512]       2 MB
#define OFF_WQB    (0x680000)                // bf16[512][512]        512 KB
#define OFF_WKB    (0x700000)
#define OFF_WVB    (0x780000)
#define OFF_WOB    (0x800000)
#define OFF_W1B    (0x880000)                // bf16[2048][512]       2 MB
#define OFF_W2B    (0xA80000)                // bf16[512][2048]       2 MB
#define OFF_QM     (0xC80000)                // bf16[2048][512]       2 MB  (later: f32 partial x1 spans QM+KM)
#define OFF_KM     (0xE80000)                // bf16[2048][512]       2 MB
#define OFF_VT     (0x1080000)               // bf16[512][2048]       2 MB  (later: f32 partial x1 spans VT+CTX)
#define OFF_CTX    (0x1280000)               // bf16[2048][512]       2 MB
#define OFF_ATMP   (0x1480000)               // f32 [2048][512]       4 MB
#define OFF_H1     (0x1880000)               // f32 [2048][512]       4 MB
#define OFF_H1B    (0x1C80000)               // bf16[2048][512]       2 MB
#define OFF_MID    (0x1E80000)               // bf16[2048][2048]      8 MB  (earlier: attn partial O f32 [2][2048][512])
#define OFF_FFN2   (0x2680000)               // f32 [2048][512]       4 MB  (earlier: attn partial ml)
// total 44.5 MB

__device__ __forceinline__ unsigned short f2bf(float f) {
  union { float f; unsigned u; } c; c.f = f;
  unsigned r = c.u + 0x7FFFu + ((c.u >> 16) & 1u);   // RNE
  return (unsigned short)(r >> 16);
}

// global -> LDS async, 16B per lane. HW writes LDS at wave-uniform base + lane*16.
typedef const __attribute__((address_space(1))) unsigned int* as1_u32p;
typedef __attribute__((address_space(3))) unsigned int* as3_u32p;
__device__ __forceinline__ void gload_lds16(const void* g, void* l) {
  __builtin_amdgcn_global_load_lds((as1_u32p)g, (as3_u32p)l, 16, 0, 0);
}

// ---------------------------------------------------------------------------
// fused f32 -> bf16 conversion for all 7 arrays (4 elems/thread)
// ---------------------------------------------------------------------------
__global__ void cvt_all_kernel(const float* __restrict__ x,
                               const float* __restrict__ wq, const float* __restrict__ wk,
                               const float* __restrict__ wv, const float* __restrict__ wo,
                               const float* __restrict__ w1, const float* __restrict__ w2,
                               unsigned short* __restrict__ xb,
                               unsigned short* __restrict__ wqb, unsigned short* __restrict__ wkb,
                               unsigned short* __restrict__ wvb, unsigned short* __restrict__ wob,
                               unsigned short* __restrict__ w1b, unsigned short* __restrict__ w2b) {
  int i = blockIdx.x * 256 + threadIdx.x;       // 0 .. 1048575
  const float* src; unsigned short* dst; int off;
  if (i < 262144)      { src = x;  dst = xb;  off = i; }
  else if (i < 327680) { src = wq; dst = wqb; off = i - 262144; }
  else if (i < 393216) { src = wk; dst = wkb; off = i - 327680; }
  else if (i < 458752) { src = wv; dst = wvb; off = i - 393216; }
  else if (i < 524288) { src = wo; dst = wob; off = i - 458752; }
  else if (i < 786432) { src = w1; dst = w1b; off = i - 524288; }
  else                 { src = w2; dst = w2b; off = i - 786432; }
  float4 v = ((const float4*)src)[off];
  unsigned p0 = (unsigned)f2bf(v.x) | ((unsigned)f2bf(v.y) << 16);
  unsigned p1 = (unsigned)f2bf(v.z) | ((unsigned)f2bf(v.w) << 16);
  ((uint2*)dst)[off] = make_uint2(p0, p1);
}

// ---------------------------------------------------------------------------
// adj (f32 0/1) -> row bitsets, u32 [2048][64]
// ---------------------------------------------------------------------------
__global__ void pack_adj_kernel(const float* __restrict__ adj, uint32_t* __restrict__ adjb) {
  int i = blockIdx.x;
  int tid = threadIdx.x, wid = tid >> 6, lane = tid & 63;
  for (int it = 0; it < 8; ++it) {
    int jbase = it * 256 + wid * 64;
    int j = jbase + lane;
    unsigned long long m = __ballot(adj[(size_t)i * 2048 + j] > 0.0f);
    int w32 = jbase >> 5;
    if (lane == 0)  adjb[i * 64 + w32]     = (uint32_t)m;
    if (lane == 32) adjb[i * 64 + w32 + 1] = (uint32_t)(m >> 32);
  }
}

// ---------------------------------------------------------------------------
// BFS truncated at depth 9 -> dist u8 in [0,10].
// One block (4 waves) per source row; LDS frontier list; dwordx4 gather
// (4 adj rows / instruction), 4-deep ILP.
// ---------------------------------------------------------------------------
__global__ __launch_bounds__(256) void bfs_kernel(const uint32_t* __restrict__ adjb,
                                                  uint8_t* __restrict__ dist) {
  int i = blockIdx.x;
  int tid = threadIdx.x, wid = tid >> 6, lane = tid & 63;

  __shared__ uint16_t list_s[2112];
  __shared__ uint4 comb_v[4][64];
  __shared__ uint32_t wtot[4];
  const uint32_t* comb_u = (const uint32_t*)comb_v;

  uint32_t adjrow = adjb[i * 64 + lane];
  uint32_t diagm  = (lane == (i >> 5)) ? (1u << (i & 31)) : 0u;
  uint32_t front  = adjrow & ~diagm;          // exactly distance-1 nodes
  uint32_t reach  = front | diagm;
  uint32_t dp0 = front;
  uint32_t dp1 = ~(front | diagm);
  uint32_t dp2 = 0u;
  uint32_t dp3 = dp1;

  for (int t = 2; t <= 9; ++t) {
    uint32_t fw = __shfl(front, wid * 16 + (lane >> 2));
    uint32_t fb = (fw >> ((lane & 3) * 8)) & 0xFFu;
    int cnt = __popc(fb);
    int scan = cnt;                          // wave-inclusive scan
    #pragma unroll
    for (int o = 1; o < 64; o <<= 1) {
      int u = __shfl_up(scan, o);
      if (lane >= o) scan += u;
    }
    if (lane == 63) wtot[wid] = (uint32_t)scan;
    __syncthreads();
    int w0 = (int)wtot[0], w1 = (int)wtot[1], w2 = (int)wtot[2], w3 = (int)wtot[3];
    int cnt_total = w0 + w1 + w2 + w3;
    if (cnt_total == 0) break;
    int base0 = (wid > 0 ? w0 : 0) + (wid > 1 ? w1 : 0) + (wid > 2 ? w2 : 0);
    int off = base0 + scan - cnt;            // exclusive offset for this thread
    int nodebase = tid * 8;
    while (fb) {
      int b = __builtin_ctz(fb);
      fb &= fb - 1u;
      list_s[off++] = (uint16_t)(nodebase + b);
    }
    int padded = (cnt_total + 63) & ~63;
    for (int k = cnt_total + tid; k < padded; k += 256)
      list_s[k] = (uint16_t)i;               // source row: subset of reach
    __syncthreads();

    uint4 acc = make_uint4(0u, 0u, 0u, 0u);
    int wsub = (lane & 15) * 4;              // this lane's word range
    for (int base = wid * 16; base < padded; base += 64) {
      #pragma unroll
      for (int j = 0; j < 4; ++j) {
        int node = list_s[base + j * 4 + (lane >> 4)];
        uint4 v = *(const uint4*)(adjb + node * 64 + wsub);
        acc.x |= v.x; acc.y |= v.y; acc.z |= v.z; acc.w |= v.w;
      }
    }
    comb_v[wid][lane] = acc;
    __syncthreads();
    uint32_t orv = 0;
    int idx = (lane >> 2) * 4 + (lane & 3);
    #pragma unroll
    for (int w4 = 0; w4 < 4; ++w4)
      #pragma unroll
      for (int g = 0; g < 4; ++g)
        orv |= comb_u[w4 * 256 + g * 64 + idx];
    uint32_t nreach = reach | orv;
    uint32_t nf = nreach & ~reach;
    dp0 = (dp0 & ~nf) | ((t & 1) ? nf : 0u);
    dp1 = (dp1 & ~nf) | ((t & 2) ? nf : 0u);
    dp2 = (dp2 & ~nf) | ((t & 4) ? nf : 0u);
    dp3 = (dp3 & ~nf) | ((t & 8) ? nf : 0u);
    front = nf;
    reach = nreach;
    __syncthreads();                         // protect list_s/comb for next level
  }

  uint32_t p0 = __shfl(dp0, wid * 16 + (lane >> 2));
  uint32_t p1 = __shfl(dp1, wid * 16 + (lane >> 2));
  uint32_t p2 = __shfl(dp2, wid * 16 + (lane >> 2));
  uint32_t p3 = __shfl(dp3, wid * 16 + (lane >> 2));
  int sh = (lane & 3) * 8;
  uint32_t lo = 0, hi = 0;
  #pragma unroll
  for (int j = 0; j < 4; ++j) {
    int bit = sh + j;
    uint32_t d = ((p0 >> bit) & 1u) | (((p1 >> bit) & 1u) << 1) |
                 (((p2 >> bit) & 1u) << 2) | (((p3 >> bit) & 1u) << 3);
    lo |= d << (8 * j);
  }
  #pragma unroll
  for (int j = 0; j < 4; ++j) {
    int bit = sh + 4 + j;
    uint32_t d = ((p0 >> bit) & 1u) | (((p1 >> bit) & 1u) << 1) |
                 (((p2 >> bit) & 1u) << 2) | (((p3 >> bit) & 1u) << 3);
    hi |= d << (8 * j);
  }
  ((uint2*)(dist + (size_t)i * 2048))[tid] = make_uint2(lo, hi);
}

// ---------------------------------------------------------------------------
// GEMM core: C[64,64] += A[64,kc] * W[64,kc]^T  (bf16 row-major, ld = K)
// 4 waves (2x2), each wave 32x32 (2x2 frags). BK=64, 2 barriers/K-tile.
// Same XOR chunk-swizzle as before (row stride is still 128 B).
// ---------------------------------------------------------------------------
__device__ __forceinline__ void gemm_core64(const short* __restrict__ A,
                                            const short* __restrict__ W,
                                            int K, int kstart, int kc,
                                            int am0, int bn0,
                                            f32x4 acc[2][2], char* smem) {
  int tid = threadIdx.x, wid = tid >> 6, lane = tid & 63;
  int c15 = lane & 15, g = lane >> 4;
  int wm = wid >> 1, wn = wid & 1;
  char* As = smem;              // 8 KB
  char* Bs = smem + 8192;       // 8 KB

  for (int kt = kstart; kt < kstart + kc; kt += 64) {
    __syncthreads();   // previous tile's LDS reads done
    #pragma unroll
    for (int i = 0; i < 2; ++i) {
      int c   = i * 256 + tid;
      int row = c >> 3;
      int kg  = (c & 7) ^ (row & 7);
      gload_lds16(A + (size_t)(am0 + row) * K + kt + kg * 8,
                  As + i * 4096 + wid * 1024);
      gload_lds16(W + (size_t)(bn0 + row) * K + kt + kg * 8,
                  Bs + i * 4096 + wid * 1024);
    }
    __syncthreads();   // staging complete (implicit vmcnt(0))
    #pragma unroll
    for (int ks = 0; ks < 2; ++ks) {
      short8 af[2], bfr[2];
      #pragma unroll
      for (int mt = 0; mt < 2; ++mt) {
        int row   = wm * 32 + mt * 16 + c15;
        int chunk = (ks * 4 + g) ^ (row & 7);
        af[mt] = *(const short8*)(As + row * 128 + chunk * 16);
      }
      #pragma unroll
      for (int nt = 0; nt < 2; ++nt) {
        int row   = wn * 32 + nt * 16 + c15;
        int chunk = (ks * 4 + g) ^ (row & 7);
        bfr[nt] = *(const short8*)(Bs + row * 128 + chunk * 16);
      }
      #pragma unroll
      for (int mt = 0; mt < 2; ++mt)
        #pragma unroll
        for (int nt = 0; nt < 2; ++nt)
          acc[mt][nt] = __builtin_amdgcn_mfma_f32_16x16x32_bf16(af[mt], bfr[nt], acc[mt][nt], 0, 0, 0);
    }
  }
}

// MODE 0: QKV (3 weight regions; q,k -> bf16 row-major; v -> bf16 transposed vT[d][n])
// MODE 1: f32 out (+bias iff z==0); split-K partial selected by blockIdx.z
// MODE 2: bf16 out + bias + exact GELU
template <int MODE>
__global__ __launch_bounds__(256) void gemm_kernel(
    const short* __restrict__ A,
    const short* __restrict__ W0, const short* __restrict__ W1, const short* __restrict__ W2,
    const float* __restrict__ b0, const float* __restrict__ b1, const float* __restrict__ b2,
    unsigned short* __restrict__ outq, unsigned short* __restrict__ outk, unsigned short* __restrict__ outv,
    float* __restrict__ of0, float* __restrict__ of1, float* __restrict__ of2, float* __restrict__ of3,
    unsigned short* __restrict__ outb,
    int K, int kc, int ldo) {
  __shared__ __align__(16) char smem[16384];
  int by = blockIdx.y, z = blockIdx.z;
  const short* W; const float* bias; int bn0;
  int region = 0;
  if (MODE == 0) {
    region = by >> 3;
    W    = (region == 0) ? W0 : (region == 1) ? W1 : W2;
    bias = (region == 0) ? b0 : (region == 1) ? b1 : b2;
    bn0  = (by & 7) * 64;
  } else {
    W = W0; bias = b0; bn0 = by * 64;
  }
  int am0 = blockIdx.x * 64;

  f32x4 acc[2][2] = {};
  gemm_core64(A, W, K, z * kc, kc, am0, bn0, acc, smem);

  int tid = threadIdx.x, wid = tid >> 6, lane = tid & 63;
  int c15 = lane & 15, g = lane >> 4;
  int wm = wid >> 1, wn = wid & 1;
  float* of = (MODE == 1) ? ((z == 0) ? of0 : (z == 1) ? of1 : (z == 2) ? of2 : of3) : of0;

  #pragma unroll
  for (int mt = 0; mt < 2; ++mt)
    #pragma unroll
    for (int nt = 0; nt < 2; ++nt)
      #pragma unroll
      for (int r = 0; r < 4; ++r) {
        int row = am0 + wm * 32 + mt * 16 + g * 4 + r;   // D: row=(lane>>4)*4+reg
        int col = bn0 + wn * 32 + nt * 16 + c15;         // D: col=lane&15
        if (MODE == 0) {
          float v = acc[mt][nt][r] + bias[col];
          if (region == 0)      outq[(size_t)row * 512 + col] = f2bf(v);
          else if (region == 1) outk[(size_t)row * 512 + col] = f2bf(v);
          else                  outv[(size_t)col * 2048 + row] = f2bf(v);   // vT[d][n]
        } else if (MODE == 1) {
          float v = acc[mt][nt][r] + ((z == 0) ? bias[col] : 0.0f);
          of[(size_t)row * ldo + col] = v;
        } else {
          float v = acc[mt][nt][r] + bias[col];
          float gv = 0.5f * v * (1.0f + erff(v * 0.70710678118654752f));
          outb[(size_t)row * ldo + col] = f2bf(gv);
        }
      }
}

// ---------------------------------------------------------------------------
// Flash attention (KV-split x2 across blockIdx.z).
// Block (qt, h, z): q rows [qt*16,+16), head h, KV cols [z*1024,+1024).
// 4 waves; wave w owns 256 KV cols (independent online softmax); in-block LDS
// combine produces unnormalized partial (m*,l*,O*) written to po/pml.
// ---------------------------------------------------------------------------
__global__ __launch_bounds__(256, 4) void attn_kernel(
    const short* __restrict__ qm, const short* __restrict__ km,
    const short* __restrict__ vT, const uint8_t* __restrict__ dist,
    const float* __restrict__ semb, float* __restrict__ po, float* __restrict__ pml) {
  int qt = blockIdx.x, h = blockIdx.y, z = blockIdx.z;
  int tid = threadIdx.x, wid = tid >> 6, lane = tid & 63;
  int c15 = lane & 15, g = lane >> 4;

  __shared__ __align__(16) char lds[16896];
  __shared__ float semb_s[12];
  if (tid < 11) semb_s[tid] = semb[tid];
  __syncthreads();

  char* pbuf = lds + wid * 2048;
  uint8_t* dbuf = (uint8_t*)(lds + 8192 + wid * 1024);

  int qr0 = qt * 16;

  short8 aq[2];
  #pragma unroll
  for (int ks = 0; ks < 2; ++ks)
    aq[ks] = *(const short8*)(qm + (size_t)(qr0 + c15) * 512 + h * 64 + ks * 32 + g * 8);

  f32x4 o[4] = {};
  float m[4], l[4];
  #pragma unroll
  for (int r = 0; r < 4; ++r) { m[r] = -1e30f; l[r] = 0.0f; }

  for (int t = 0; t < 4; ++t) {
    int kv0 = z * 1024 + wid * 256 + t * 64;

    // stage dist tile [16 rows x 64 cols] -> dbuf (one instruction)
    gload_lds16(dist + (size_t)(qr0 + (lane >> 2)) * 2048 + kv0 + (lane & 3) * 16, dbuf);

    // --- S = Q K^T ---
    f32x4 sacc[4] = {};
    #pragma unroll
    for (int nt = 0; nt < 4; ++nt)
      #pragma unroll
      for (int ks = 0; ks < 2; ++ks) {
        short8 bk = *(const short8*)(km + (size_t)(kv0 + nt * 16 + c15) * 512 + h * 64 + ks * 32 + g * 8);
        sacc[nt] = __builtin_amdgcn_mfma_f32_16x16x32_bf16(aq[ks], bk, sacc[nt], 0, 0, 0);
      }

    // dist tile staged? (gload_lds completion is vmcnt; compiler can't track)
    asm volatile("s_waitcnt vmcnt(0)" ::: "memory");
    __builtin_amdgcn_sched_barrier(0);

    // --- scale + spatial bias; row stats ---
    float sv[4][4];
    float rmax[4];
    #pragma unroll
    for (int r = 0; r < 4; ++r) rmax[r] = -1e30f;
    #pragma unroll
    for (int nt = 0; nt < 4; ++nt)
      #pragma unroll
      for (int r = 0; r < 4; ++r) {
        float b = semb_s[dbuf[(g * 4 + r) * 64 + nt * 16 + c15]];
        float s = sacc[nt][r] * 0.125f + b;
        sv[nt][r] = s;
        rmax[r] = fmaxf(rmax[r], s);
      }
    #pragma unroll
    for (int r = 0; r < 4; ++r) {
      rmax[r] = fmaxf(rmax[r], __shfl_xor(rmax[r], 1));
      rmax[r] = fmaxf(rmax[r], __shfl_xor(rmax[r], 2));
      rmax[r] = fmaxf(rmax[r], __shfl_xor(rmax[r], 4));
      rmax[r] = fmaxf(rmax[r], __shfl_xor(rmax[r], 8));
    }

    // --- online softmax update ---
    float pscale[4], rsum[4];
    #pragma unroll
    for (int r = 0; r < 4; ++r) {
      float mn = fmaxf(m[r], rmax[r]);
      pscale[r] = __expf(m[r] - mn);
      m[r] = mn;
      rsum[r] = 0.0f;
    }
    #pragma unroll
    for (int nt = 0; nt < 4; ++nt)
      #pragma unroll
      for (int r = 0; r < 4; ++r) {
        float p = __expf(sv[nt][r] - m[r]);
        sv[nt][r] = p;
        rsum[r] += p;
      }
    #pragma unroll
    for (int r = 0; r < 4; ++r) {
      rsum[r] += __shfl_xor(rsum[r], 1);
      rsum[r] += __shfl_xor(rsum[r], 2);
      rsum[r] += __shfl_xor(rsum[r], 4);
      rsum[r] += __shfl_xor(rsum[r], 8);
      l[r] = l[r] * pscale[r] + rsum[r];
    }
    #pragma unroll
    for (int dt = 0; dt < 4; ++dt)
      #pragma unroll
      for (int r = 0; r < 4; ++r)
        o[dt][r] *= pscale[r];

    // --- P -> bf16, transpose via LDS (swizzle: byte ^= (q&3)<<5) ---
    #pragma unroll
    for (int nt = 0; nt < 4; ++nt)
      #pragma unroll
      for (int r = 0; r < 4; ++r) {
        int qloc = g * 4 + r;
        int colb = (nt * 16 + c15) * 2;
        int addr = qloc * 128 + (colb ^ ((qloc & 3) << 5));
        *(unsigned short*)(pbuf + addr) = f2bf(sv[nt][r]);
      }
    short8 pa[2];
    #pragma unroll
    for (int ks = 0; ks < 2; ++ks) {
      int chunk = (ks * 4 + g) ^ ((c15 & 3) << 1);
      pa[ks] = *(const short8*)(pbuf + c15 * 128 + chunk * 16);
    }

    // --- O += P V ---
    #pragma unroll
    for (int dt = 0; dt < 4; ++dt)
      #pragma unroll
      for (int ks = 0; ks < 2; ++ks) {
        short8 bv = *(const short8*)(vT + (size_t)(h * 64 + dt * 16 + c15) * 2048 + kv0 + ks * 32 + g * 8);
        o[dt] = __builtin_amdgcn_mfma_f32_16x16x32_bf16(pa[ks], bv, o[dt], 0, 0, 0);
      }
  }

  // ---- combine per-wave partials via LDS; write unnormalized (m*,l*,O*) ----
  __syncthreads();                    // all waves done with pbuf/dbuf
  float* o_s  = (float*)lds;          // [16 dtr][256 = w*64+lane]
  float* ml_s = (float*)(lds + 16384);// [w][16 rows][2]
  #pragma unroll
  for (int dt = 0; dt < 4; ++dt)
    #pragma unroll
    for (int r = 0; r < 4; ++r)
      o_s[(dt * 4 + r) * 256 + wid * 64 + lane] = o[dt][r];
  if (c15 == 0) {
    #pragma unroll
    for (int r = 0; r < 4; ++r) {
      ml_s[wid * 32 + (g * 4 + r) * 2]     = m[r];
      ml_s[wid * 32 + (g * 4 + r) * 2 + 1] = l[r];
    }
  }
  __syncthreads();

  if (wid == 0) {
    float e[4][4], lsum[4], msv[4];
    #pragma unroll
    for (int r = 0; r < 4; ++r) {
      int row = g * 4 + r;
      float m0 = ml_s[row * 2], m1 = ml_s[32 + row * 2],
            m2 = ml_s[64 + row * 2], m3 = ml_s[96 + row * 2];
      float ms = fmaxf(fmaxf(m0, m1), fmaxf(m2, m3));
      msv[r] = ms;
      e[0][r] = __expf(m0 - ms); e[1][r] = __expf(m1 - ms);
      e[2][r] = __expf(m2 - ms); e[3][r] = __expf(m3 - ms);
      lsum[r] = ml_s[row * 2 + 1] * e[0][r] + ml_s[32 + row * 2 + 1] * e[1][r] +
                ml_s[64 + row * 2 + 1] * e[2][r] + ml_s[96 + row * 2 + 1] * e[3][r];
    }
    #pragma unroll
    for (int dt = 0; dt < 4; ++dt)
      #pragma unroll
      for (int r = 0; r < 4; ++r) {
        float comb = 0.0f;
        #pragma unroll
        for (int w = 0; w < 4; ++w)
          comb += o_s[(dt * 4 + r) * 256 + w * 64 + lane] * e[w][r];
        int q = qr0 + g * 4 + r;
        po[((size_t)z * 2048 + q) * 512 + h * 64 + dt * 16 + c15] = comb;
      }
    if (c15 == 0) {
      #pragma unroll
      for (int r = 0; r < 4; ++r) {
        int q = qr0 + g * 4 + r;
        pml[(((size_t)z * 2048 + q) * 8 + h) * 2]     = msv[r];
        pml[(((size_t)z * 2048 + q) * 8 + h) * 2 + 1] = lsum[r];
      }
    }
  }
}

// ---------------------------------------------------------------------------
// Cross-chunk attention combine: ctx = (O0 e0 + O1 e1) / (l0 e0 + l1 e1)
// ---------------------------------------------------------------------------
__global__ __launch_bounds__(256) void attn_combine_kernel(
    const float* __restrict__ po, const float* __restrict__ pml,
    unsigned short* __restrict__ ctx) {
  int q = blockIdx.x, tid = threadIdx.x;
  #pragma unroll
  for (int half = 0; half < 2; ++half) {
    int d = half * 256 + tid;
    int h = d >> 6;
    float m0 = pml[((size_t)q * 8 + h) * 2];
    float l0 = pml[((size_t)q * 8 + h) * 2 + 1];
    float m1 = pml[(((size_t)2048 + q) * 8 + h) * 2];
    float l1 = pml[(((size_t)2048 + q) * 8 + h) * 2 + 1];
    float ms = fmaxf(m0, m1);
    float e0 = __expf(m0 - ms), e1 = __expf(m1 - ms);
    float v = po[(size_t)q * 512 + d] * e0 + po[((size_t)2048 + q) * 512 + d] * e1;
    ctx[(size_t)q * 512 + d] = f2bf(v / (l0 * e0 + l1 * e1));
  }
}

// ---------------------------------------------------------------------------
// LayerNorm(a + sum of NP partials) row-wise; optional bf16 copy of output
// ---------------------------------------------------------------------------
template <int NP, bool WB>
__global__ __launch_bounds__(256) void ln_kernel(
    const float* __restrict__ a,
    const float* __restrict__ p0, const float* __restrict__ p1,
    const float* __restrict__ p2, const float* __restrict__ p3,
    const float* __restrict__ w, const float* __restrict__ bb,
    float* __restrict__ out, unsigned short* __restrict__ outb) {
  int row = blockIdx.x, tid = threadIdx.x;
  size_t base = (size_t)row * 512;
  float v0 = a[base + tid]       + p0[base + tid];
  float v1 = a[base + tid + 256] + p0[base + tid + 256];
  if (NP > 1) { v0 += p1[base + tid]; v1 += p1[base + tid + 256]; }
  if (NP > 2) { v0 += p2[base + tid]; v1 += p2[base + tid + 256]; }
  if (NP > 3) { v0 += p3[base + tid]; v1 += p3[base + tid + 256]; }
  float s = v0 + v1, q = v0 * v0 + v1 * v1;
  for (int o = 32; o > 0; o >>= 1) { s += __shfl_down(s, o); q += __shfl_down(q, o); }
  __shared__ float rs[4], rq[4], bc[2];
  int wid = tid >> 6, lane = tid & 63;
  if (lane == 0) { rs[wid] = s; rq[wid] = q; }
  __syncthreads();
  if (tid == 0) {
    float S = rs[0] + rs[1] + rs[2] + rs[3];
    float Q = rq[0] + rq[1] + rq[2] + rq[3];
    float mu = S * (1.0f / 512.0f);
    bc[0] = mu;
    bc[1] = Q * (1.0f / 512.0f) - mu * mu;
  }
  __syncthreads();
  float mu = bc[0], inv = rsqrtf(bc[1] + 1e-5f);
  float o0 = (v0 - mu) * inv * w[tid] + bb[tid];
  float o1 = (v1 - mu) * inv * w[tid + 256] + bb[tid + 256];
  out[base + tid] = o0;
  out[base + tid + 256] = o1;
  if (WB) {
    outb[base + tid] = f2bf(o0);
    outb[base + tid + 256] = f2bf(o1);
  }
}

// ---------------------------------------------------------------------------
extern "C" void kernel_launch(void* const* d_in, const int* in_sizes, int n_in,
                              void* d_out, int out_size, void* d_ws, size_t ws_size,
                              hipStream_t stream) {
  (void)in_sizes; (void)n_in; (void)out_size; (void)ws_size;
  const float* x    = (const float*)d_in[0];
  const float* adj  = (const float*)d_in[1];
  const float* semb = (const float*)d_in[2];
  const float* wq   = (const float*)d_in[3];
  const float* bq   = (const float*)d_in[4];
  const float* wk   = (const float*)d_in[5];
  const float* bk   = (const float*)d_in[6];
  const float* wv   = (const float*)d_in[7];
  const float* bv   = (const float*)d_in[8];
  const float* wo   = (const float*)d_in[9];
  const float* bo   = (const float*)d_in[10];
  const float* ln1w = (const float*)d_in[11];
  const float* ln1b = (const float*)d_in[12];
  const float* w1   = (const float*)d_in[13];
  const float* b1   = (const float*)d_in[14];
  const float* w2   = (const float*)d_in[15];
  const float* b2   = (const float*)d_in[16];
  const float* ln2w = (const float*)d_in[17];
  const float* ln2b = (const float*)d_in[18];
  float* out = (float*)d_out;
  char* ws = (char*)d_ws;

  uint32_t*       adjb = (uint32_t*)(ws + OFF_ADJB);
  uint8_t*        dist = (uint8_t*)(ws + OFF_DIST);
  unsigned short* xb   = (unsigned short*)(ws + OFF_XB);
  unsigned short* wqb  = (unsigned short*)(ws + OFF_WQB);
  unsigned short* wkb  = (unsigned short*)(ws + OFF_WKB);
  unsigned short* wvb  = (unsigned short*)(ws + OFF_WVB);
  unsigned short* wob  = (unsigned short*)(ws + OFF_WOB);
  unsigned short* w1b  = (unsigned short*)(ws + OFF_W1B);
  unsigned short* w2b  = (unsigned short*)(ws + OFF_W2B);
  unsigned short* qm   = (unsigned short*)(ws + OFF_QM);
  unsigned short* km   = (unsigned short*)(ws + OFF_KM);
  unsigned short* vT   = (unsigned short*)(ws + OFF_VT);
  unsigned short* ctx  = (unsigned short*)(ws + OFF_CTX);
  float*          atmp = (float*)(ws + OFF_ATMP);
  float*          h1   = (float*)(ws + OFF_H1);
  unsigned short* h1b  = (unsigned short*)(ws + OFF_H1B);
  unsigned short* mid  = (unsigned short*)(ws + OFF_MID);
  float*          ffn2 = (float*)(ws + OFF_FFN2);
  // reused (liveness-checked) regions:
  float* po    = (float*)(ws + OFF_MID);    // attn partial O  [2][2048][512] f32 (dead before FFN1 writes mid)
  float* pml   = (float*)(ws + OFF_FFN2);   // attn partial ml [2][2048][8][2] f32 (dead before FFN2 writes)
  float* distf = (float*)(ws + OFF_DIST);   // split-K partial (dist dead after attn)
  float* qmf   = (float*)(ws + OFF_QM);     // split-K partial (spans qm+km, dead after attn)
  float* vtf   = (float*)(ws + OFF_VT);     // split-K partial (spans vT+ctx, dead after out-proj)

  // ---- dtype conversions (fused) ----
  cvt_all_kernel<<<4096, 256, 0, stream>>>(x, wq, wk, wv, wo, w1, w2,
                                           xb, wqb, wkb, wvb, wob, w1b, w2b);

  // ---- spatial distances ----
  pack_adj_kernel<<<2048, 256, 0, stream>>>(adj, adjb);
  bfs_kernel<<<2048, 256, 0, stream>>>(adjb, dist);

  // ---- QKV projection (q,k row-major; v transposed) ----
  gemm_kernel<0><<<dim3(32, 24), 256, 0, stream>>>(
      (const short*)xb, (const short*)wqb, (const short*)wkb, (const short*)wvb,
      bq, bk, bv, qm, km, vT,
      nullptr, nullptr, nullptr, nullptr, nullptr, 512, 512, 512);

  // ---- attention (KV-split x2) + combine ----
  attn_kernel<<<dim3(128, 8, 2), 256, 0, stream>>>(
      (const short*)qm, (const short*)km, (const short*)vT, dist, semb, po, pml);
  attn_combine_kernel<<<2048, 256, 0, stream>>>(po, pml, ctx);

  // ---- output projection (split-K x2) ----
  gemm_kernel<1><<<dim3(32, 8, 2), 256, 0, stream>>>(
      (const short*)ctx, (const short*)wob, nullptr, nullptr,
      bo, nullptr, nullptr, nullptr, nullptr, nullptr,
      atmp, distf, nullptr, nullptr, nullptr, 512, 256, 512);

  // ---- LN1 (x + atmp + distf) ----
  ln_kernel<2, true><<<2048, 256, 0, stream>>>(x, atmp, distf, nullptr, nullptr,
                                               ln1w, ln1b, h1, h1b);

  // ---- FFN1 (GELU -> bf16 mid) ----
  gemm_kernel<2><<<dim3(32, 32), 256, 0, stream>>>(
      (const short*)h1b, (const short*)w1b, nullptr, nullptr,
      b1, nullptr, nullptr, nullptr, nullptr, nullptr,
      nullptr, nullptr, nullptr, nullptr, mid, 512, 512, 2048);

  // ---- FFN2 (split-K x4) ----
  gemm_kernel<1><<<dim3(32, 8, 4), 256, 0, stream>>>(
      (const short*)mid, (const short*)w2b, nullptr, nullptr,
      b2, nullptr, nullptr, nullptr, nullptr, nullptr,
      ffn2, distf, qmf, vtf, nullptr, 2048, 512, 512);

  // ---- LN2 (h1 + 4 partials) -> output ----
  ln_kernel<4, false><<<2048, 256, 0, stream>>>(h1, ffn2, distf, qmf, vtf,
                                                ln2w, ln2b, out, nullptr);
}